// Round 1
// baseline (208.674 us; speedup 1.0000x reference)
//
#include <hip/hip_runtime.h>
#include <hip/hip_bf16.h>
#include <math.h>

#define EMBED_DIM 1024
#define NUM_HEADS 16
#define HEAD_DIM 64
#define BATCH 2
#define SEQ 2048

using short8  = __attribute__((ext_vector_type(8))) short;
using floatx4 = __attribute__((ext_vector_type(4))) float;

__device__ __forceinline__ ushort f2bf(float f) {
    unsigned u = __float_as_uint(f);
    u = (u + 0x7FFFu + ((u >> 16) & 1u)) >> 16;   // RNE
    return (ushort)u;
}

// pack two floats to bf16x2 (half-up rounding — P values are in [0,1], fine)
__device__ __forceinline__ unsigned bfpack2(float a, float b) {
    return ((__float_as_uint(a) + 0x8000u) >> 16) |
           (((__float_as_uint(b) + 0x8000u) >> 16) << 16);
}

// async global->LDS, 16B per lane; LDS dest = wave-uniform base + lane*16.
__device__ __forceinline__ void load_lds16(const ushort* g, ushort* l) {
    __builtin_amdgcn_global_load_lds(
        (const __attribute__((address_space(1))) void*)g,
        (__attribute__((address_space(3))) void*)l, 16, 0, 0);
}

// ---------------------------------------------------------------------------
// Fused prep: cast x -> bf16, transpose+cast W_qkv and W_out.
// ---------------------------------------------------------------------------
__device__ __forceinline__ void tc_tile(
    const float* __restrict__ W, ushort* __restrict__ Wt,
    int K, int N, int n0, int k0, float (*t)[65])
{
    const int c = threadIdx.x & 63, r0 = (threadIdx.x >> 6) * 16;
    #pragma unroll
    for (int r = 0; r < 16; ++r)
        t[r0 + r][c] = W[(size_t)(k0 + r0 + r) * N + n0 + c];
    __syncthreads();
    #pragma unroll
    for (int r = 0; r < 16; ++r)
        Wt[(size_t)(n0 + r0 + r) * K + k0 + c] = f2bf(t[c][r0 + r]);
}

__global__ __launch_bounds__(256) void prep_all(
    const float* __restrict__ x, const float* __restrict__ W_qkv,
    const float* __restrict__ W_out,
    ushort* __restrict__ xb, ushort* __restrict__ Wqb_t, ushort* __restrict__ Wob_t)
{
    __shared__ float t[64][65];
    const int bx = blockIdx.x;
    if (bx < 4096) {
        int i = (bx * 256 + threadIdx.x) * 4;
        float4 v = *(const float4*)&x[i];
        ushort4 o = { f2bf(v.x), f2bf(v.y), f2bf(v.z), f2bf(v.w) };
        *(ushort4*)&xb[i] = o;
    } else if (bx < 4096 + 768) {
        int b = bx - 4096;
        tc_tile(W_qkv, Wqb_t, 1024, 3072, (b % 48) * 64, (b / 48) * 64, t);
    } else {
        int b = bx - 4864;
        tc_tile(W_out, Wob_t, 1024, 1024, (b % 16) * 64, (b / 16) * 64, t);
    }
}

// ---------------------------------------------------------------------------
// Old 128x128 double-buffered core — still used by gemm_out (grid there is
// only 8x32; the 256^2 template would leave 3/4 of the chip idle).
// ---------------------------------------------------------------------------
#define GK 1024

__device__ __forceinline__ void gemm_core(
    const ushort* __restrict__ A, const ushort* __restrict__ Bt,
    int m0, int n0, ushort* As0, ushort* As1, ushort* Bs0, ushort* Bs1,
    floatx4 acc[4][4])
{
    const int tid  = threadIdx.x;
    const int w    = tid >> 6;
    const int lane = tid & 63;
    const int col  = lane & 15;
    const int quad = lane >> 4;
    const int wm   = w >> 1, wn = w & 1;

    #pragma unroll
    for (int i = 0; i < 4; ++i)
        #pragma unroll
        for (int j = 0; j < 4; ++j)
            acc[i][j] = (floatx4){0.f, 0.f, 0.f, 0.f};

    const int o0   = w * 2048 + lane * 16;   // byte offset in 8KB tile
    const int row0 = o0 >> 6;
    const int ke0  = (o0 & 63) >> 1;
    const int loff = (w * 2048) >> 1;        // LDS element offset for this wave

    const ushort* ga = A  + (size_t)(m0 + row0) * GK + ke0;
    const ushort* gb = Bt + (size_t)(n0 + row0) * GK + ke0;

    #pragma unroll
    for (int t = 0; t < 2; ++t) {
        load_lds16(ga + (size_t)t * 16 * GK, As0 + loff + t * 512);
        load_lds16(gb + (size_t)t * 16 * GK, Bs0 + loff + t * 512);
    }
    __syncthreads();

    for (int k0 = 0; k0 < GK; k0 += 32) {
        const int cur = (k0 >> 5) & 1;
        ushort* Ac = cur ? As1 : As0;
        ushort* Bc = cur ? Bs1 : Bs0;
        ushort* An = cur ? As0 : As1;
        ushort* Bn = cur ? Bs0 : Bs1;

        if (k0 + 32 < GK) {   // issue prefetch BEFORE compute
            #pragma unroll
            for (int t = 0; t < 2; ++t) {
                load_lds16(ga + (k0 + 32) + (size_t)t * 16 * GK, An + loff + t * 512);
                load_lds16(gb + (k0 + 32) + (size_t)t * 16 * GK, Bn + loff + t * 512);
            }
        }

        short8 af[4], bf[4];
        #pragma unroll
        for (int i = 0; i < 4; ++i)
            af[i] = *(const short8*)&Ac[(wm * 64 + i * 16 + col) * 32 + quad * 8];
        #pragma unroll
        for (int j = 0; j < 4; ++j)
            bf[j] = *(const short8*)&Bc[(wn * 64 + j * 16 + col) * 32 + quad * 8];
        #pragma unroll
        for (int i = 0; i < 4; ++i)
            #pragma unroll
            for (int j = 0; j < 4; ++j)
                acc[i][j] = __builtin_amdgcn_mfma_f32_16x16x32_bf16(af[i], bf[j], acc[i][j], 0, 0, 0);

        __syncthreads();
    }
}

// ---------------------------------------------------------------------------
// NEW: qkv projection as the 256^2 8-phase schedule (T1+T2+T3+T4+T5).
//   BM=BN=256, BK=64, 8 waves (2M x 4N), per-wave 128x64 output (acc[8][4]).
//   LDS: A/B tiles [256][64] bf16, double-buffered = 128 KiB.
//   Per K-tile: 4 phases, each {ds_read frag subtile | stage 1 half-tile |
//   raw s_barrier | lgkmcnt(0) | setprio(1) 16xMFMA setprio(0) | raw s_barrier}.
//   Staging stream (one half-tile = 2 global_load_lds per phase):
//     tP1: Bh0(t+1)  tP2: Bh1(t+1)  tP3: Ah0(t+2)  tP4: Ah1(t+2)
//   Counted wait: single vmcnt(4) at tP4 — drains all of tile t+1, leaves the
//   two t+2 A-halves in flight. Never vmcnt(0) in steady state.
//   Overwrite safety: per-wave A-LDS reads complete by P2 (A-frags cached in
//   regs, reused at P4), so the t+2 A-half issued at P3/P4 (post-P2-barrier)
//   cannot land before the last A read. B region of buf[cur] is overwritten
//   only at (t+1)P1/P2, after tile t's P4-end barrier.
//   Swizzle (both-sides): LDS linear slot y holds logical y ^ ((row&7)<<4);
//   gload_lds source is pre-swizzled per-lane, ds_read applies the same XOR.
// ---------------------------------------------------------------------------
#define NKT 16            // K / 64
#define TILE_U 16384      // ushorts per 256x64 tile

#define MFMA_BF16(a, b, c) \
    (c) = __builtin_amdgcn_mfma_f32_16x16x32_bf16((a), (b), (c), 0, 0, 0)

#define STAGE(GBASE, LDSARR, BUF, KT, H) do {                                  \
    const ushort* _g = (GBASE) + (size_t)(H) * 128 * GK + (size_t)(KT) * 64;   \
    ushort* _l = (LDSARR) + (BUF) * TILE_U + (H) * 8192 + w * 512;             \
    load_lds16(_g + so0, _l);                                                  \
    load_lds16(_g + so1, _l + 4096);                                           \
} while (0)

__global__ __launch_bounds__(512, 2) void gemm_qkv_8ph(
    const ushort* __restrict__ A, const ushort* __restrict__ Bt,
    const float* __restrict__ bias,
    ushort* __restrict__ Qb, ushort* __restrict__ Kb, ushort* __restrict__ Vt)
{
    __shared__ __align__(16) ushort As[2 * TILE_U];   // 64 KiB
    __shared__ __align__(16) ushort Bs[2 * TILE_U];   // 64 KiB

    // T1: bijective XCD swizzle, 192 blocks = 8 XCDs x 24
    const int bid = blockIdx.x;
    const int swz = (bid & 7) * 24 + (bid >> 3);
    const int bx = swz % 12, by = swz / 12;
    const int n0 = bx * 256, m0 = by * 256;

    const int tid  = threadIdx.x;
    const int w    = tid >> 6;
    const int lane = tid & 63;
    const int col  = lane & 15;
    const int quad = lane >> 4;
    const int wm   = w >> 2, wn = w & 3;

    // staging: per-lane pre-swizzled global offsets (ushort units), j = 0,1
    // linear LDS byte y = j*8192 + w*1024 + lane*16  ->  row = y>>7,
    // logical col-bytes = (y&127) ^ ((row&7)<<4)
    const int srow = w * 8 + (lane >> 3);
    const int scx  = ((lane & 7) ^ (lane >> 3)) << 3;          // ushorts
    const size_t so0 = (size_t)srow * GK + scx;
    const size_t so1 = so0 + (size_t)64 * GK;

    const ushort* gA = A  + (size_t)m0 * GK;
    const ushort* gB = Bt + (size_t)n0 * GK;

    // T2: swizzled ds_read k-offsets (ushort units) — same XOR involution
    const int kb0 = (quad * 8) ^ ((col & 7) << 3);             // kk = 0
    const int kb1 = (32 + quad * 8) ^ ((col & 7) << 3);        // kk = 1
    const int arow = (wm * 128 + col) * 64;
    const int brow = (wn * 64 + col) * 64;

    floatx4 acc[8][4];
    #pragma unroll
    for (int i = 0; i < 8; ++i)
        #pragma unroll
        for (int j = 0; j < 4; ++j)
            acc[i][j] = (floatx4){0.f, 0.f, 0.f, 0.f};

    // prologue: tile0 fully + tile1 A-halves; drain tile0, keep Ah(1) in flight
    STAGE(gA, As, 0, 0, 0); STAGE(gA, As, 0, 0, 1);
    STAGE(gB, Bs, 0, 0, 0); STAGE(gB, Bs, 0, 0, 1);
    STAGE(gA, As, 1, 1, 0); STAGE(gA, As, 1, 1, 1);
    asm volatile("s_waitcnt vmcnt(4)" ::: "memory");
    __builtin_amdgcn_s_barrier();

    for (int t = 0; t < NKT; ++t) {
        const int cur = t & 1;
        const ushort* Ab = As + cur * TILE_U;
        const ushort* Bb = Bs + cur * TILE_U;
        const int rem = NKT - 1 - t;

        short8 af0[4][2], af1[4][2], bf0[2][2], bf1[2][2];

        // ---- phase 1: read A-ih0 (8) + B-jh0 (4); stage Bh0(t+1); C(0,0) ----
        #pragma unroll
        for (int i = 0; i < 4; ++i) {
            af0[i][0] = *(const short8*)&Ab[arow + i * 1024 + kb0];
            af0[i][1] = *(const short8*)&Ab[arow + i * 1024 + kb1];
        }
        #pragma unroll
        for (int j = 0; j < 2; ++j) {
            bf0[j][0] = *(const short8*)&Bb[brow + j * 1024 + kb0];
            bf0[j][1] = *(const short8*)&Bb[brow + j * 1024 + kb1];
        }
        if (rem >= 1) STAGE(gB, Bs, cur ^ 1, t + 1, 0);
        __builtin_amdgcn_s_barrier();
        asm volatile("s_waitcnt lgkmcnt(0)" ::: "memory");
        __builtin_amdgcn_s_setprio(1);
        #pragma unroll
        for (int i = 0; i < 4; ++i)
            #pragma unroll
            for (int j = 0; j < 2; ++j) {
                MFMA_BF16(af0[i][0], bf0[j][0], acc[i][j]);
                MFMA_BF16(af0[i][1], bf0[j][1], acc[i][j]);
            }
        __builtin_amdgcn_s_setprio(0);
        __builtin_amdgcn_s_barrier();

        // ---- phase 2: read A-ih1 (8); stage Bh1(t+1); C(1,0) ----
        #pragma unroll
        for (int i = 0; i < 4; ++i) {
            af1[i][0] = *(const short8*)&Ab[arow + 4096 + i * 1024 + kb0];
            af1[i][1] = *(const short8*)&Ab[arow + 4096 + i * 1024 + kb1];
        }
        if (rem >= 1) STAGE(gB, Bs, cur ^ 1, t + 1, 1);
        __builtin_amdgcn_s_barrier();
        asm volatile("s_waitcnt lgkmcnt(0)" ::: "memory");
        __builtin_amdgcn_s_setprio(1);
        #pragma unroll
        for (int i = 0; i < 4; ++i)
            #pragma unroll
            for (int j = 0; j < 2; ++j) {
                MFMA_BF16(af1[i][0], bf0[j][0], acc[4 + i][j]);
                MFMA_BF16(af1[i][1], bf0[j][1], acc[4 + i][j]);
            }
        __builtin_amdgcn_s_setprio(0);
        __builtin_amdgcn_s_barrier();

        // ---- phase 3: read B-jh1 (4); stage Ah0(t+2); C(1,1) ----
        #pragma unroll
        for (int j = 0; j < 2; ++j) {
            bf1[j][0] = *(const short8*)&Bb[brow + 2048 + j * 1024 + kb0];
            bf1[j][1] = *(const short8*)&Bb[brow + 2048 + j * 1024 + kb1];
        }
        if (rem >= 2) STAGE(gA, As, cur, t + 2, 0);
        __builtin_amdgcn_s_barrier();
        asm volatile("s_waitcnt lgkmcnt(0)" ::: "memory");
        __builtin_amdgcn_s_setprio(1);
        #pragma unroll
        for (int i = 0; i < 4; ++i)
            #pragma unroll
            for (int j = 0; j < 2; ++j) {
                MFMA_BF16(af1[i][0], bf1[j][0], acc[4 + i][2 + j]);
                MFMA_BF16(af1[i][1], bf1[j][1], acc[4 + i][2 + j]);
            }
        __builtin_amdgcn_s_setprio(0);
        __builtin_amdgcn_s_barrier();

        // ---- phase 4: no reads (af0/bf1 live); stage Ah1(t+2); C(0,1) ----
        if (rem >= 2) STAGE(gA, As, cur, t + 2, 1);
        __builtin_amdgcn_s_barrier();
        __builtin_amdgcn_s_setprio(1);
        #pragma unroll
        for (int i = 0; i < 4; ++i)
            #pragma unroll
            for (int j = 0; j < 2; ++j) {
                MFMA_BF16(af0[i][0], bf1[j][0], acc[i][2 + j]);
                MFMA_BF16(af0[i][1], bf1[j][1], acc[i][2 + j]);
            }
        __builtin_amdgcn_s_setprio(0);
        if (rem >= 2)      asm volatile("s_waitcnt vmcnt(4)" ::: "memory");
        else if (rem == 1) asm volatile("s_waitcnt vmcnt(0)" ::: "memory");
        __builtin_amdgcn_s_barrier();
    }

    // ---- epilogue: bias + split/cast Q,K,V (V transposed) ----
    #pragma unroll
    for (int j = 0; j < 4; ++j) {
        const int n = n0 + wn * 64 + j * 16 + col;
        const float bj = bias[n];
        const int part = n >> 10;
        const int h = (n >> 6) & 15;
        const int d = n & 63;
        #pragma unroll
        for (int i = 0; i < 8; ++i)
            #pragma unroll
            for (int r = 0; r < 4; ++r) {
                const int m = m0 + wm * 128 + i * 16 + quad * 4 + r;
                const int b = m >> 11, s = m & 2047;
                const int bh = b * 16 + h;
                const ushort bv = f2bf(acc[i][j][r] + bj);
                if (part == 0)      Qb[((size_t)bh * SEQ + s) * 64 + d] = bv;
                else if (part == 1) Kb[((size_t)bh * SEQ + s) * 64 + d] = bv;
                else                Vt[((size_t)bh * 64 + d) * SEQ + s] = bv;
            }
    }
}

// GEMM2: out = attn_b @ W_out + b_out -> fp32 (old core)
__global__ __launch_bounds__(256) void gemm_out_mfma(
    const ushort* __restrict__ A, const ushort* __restrict__ Bt,
    const float* __restrict__ bias, float* __restrict__ out)
{
    __shared__ __align__(16) ushort As[2][128 * 32];
    __shared__ __align__(16) ushort Bs[2][128 * 32];
    const int n0 = blockIdx.x * 128;
    const int m0 = blockIdx.y * 128;

    floatx4 acc[4][4];
    gemm_core(A, Bt, m0, n0, As[0], As[1], Bs[0], Bs[1], acc);

    const int lane = threadIdx.x & 63;
    const int w    = threadIdx.x >> 6;
    const int col  = lane & 15, quad = lane >> 4;
    const int wm   = w >> 1, wn = w & 1;

    #pragma unroll
    for (int j = 0; j < 4; ++j) {
        const int n = n0 + wn * 64 + j * 16 + col;
        const float bj = bias[n];
        #pragma unroll
        for (int i = 0; i < 4; ++i)
            #pragma unroll
            for (int r = 0; r < 4; ++r) {
                const int m = m0 + wm * 64 + i * 16 + quad * 4 + r;
                out[(size_t)m * EMBED_DIM + n] = acc[i][j][r] + bj;
            }
    }
}

// ---------------------------------------------------------------------------
// Flash attention, bf16 MFMA, fragment-ordered async staging, S^T softmax,
// double-buffered K/V with issue-early prefetch (1 barrier per key-tile).
// ---------------------------------------------------------------------------
#define LP 72

__global__ __launch_bounds__(256) void attn_fused(
    const ushort* __restrict__ Qb, const ushort* __restrict__ Kb,
    const ushort* __restrict__ Vt, ushort* __restrict__ out)
{
    const int id = blockIdx.x;
    const int qt = 31 - (id >> 5);          // reversed: long blocks first (LPT)
    const int bh = id & 31;
    const int b  = bh >> 4, h = bh & 15;
    const int q0 = qt * 64;

    __shared__ __align__(16) ushort Qs[8 * 512];        // 8 KB fragment order
    __shared__ __align__(16) ushort Ks[2][8 * 512];     // 16 KB dbuf
    __shared__ __align__(16) ushort Vs[2][8 * 512];     // 16 KB dbuf
    __shared__ __align__(16) ushort Ps[64 * LP];        // 9 KB
    __shared__ __align__(16) float  ls[4][16];

    const int tid  = threadIdx.x;
    const int w    = tid >> 6;
    const int lane = tid & 63;
    const int col  = lane & 15;
    const int quad = lane >> 4;

    const ushort* kg[2];
    const ushort* vg[2];
    #pragma unroll
    for (int t = 0; t < 2; ++t) {
        kg[t] = Kb + (size_t)bh * SEQ * 64 + (size_t)(w * 16 + col) * 64 + t * 32 + quad * 8;
        vg[t] = Vt + (size_t)bh * 64 * SEQ + (size_t)(w * 16 + col) * SEQ + t * 32 + quad * 8;
    }

    {
        const ushort* Qg = Qb + ((size_t)bh * SEQ + q0) * 64;
        #pragma unroll
        for (int t = 0; t < 2; ++t) {
            load_lds16(Qg + (size_t)(w * 16 + col) * 64 + t * 32 + quad * 8,
                       &Qs[(w * 2 + t) * 512]);
            load_lds16(kg[t], &Ks[0][(w * 2 + t) * 512]);
            load_lds16(vg[t], &Vs[0][(w * 2 + t) * 512]);
            kg[t] += 64 * 64;   // -> tile 1
            vg[t] += 64;
        }
    }
    __syncthreads();

    const short8 a0 = *(const short8*)&Qs[(w * 2 + 0) * 512 + lane * 8];
    const short8 a1 = *(const short8*)&Qs[(w * 2 + 1) * 512 + lane * 8];

    floatx4 acc_o[4];
    #pragma unroll
    for (int dbi = 0; dbi < 4; ++dbi) acc_o[dbi] = (floatx4){0.f, 0.f, 0.f, 0.f};
    float l_lane = 0.f;
    const int myq = w * 16 + col;

    for (int kt = 0; kt <= qt; ++kt) {
        const int cur = kt & 1;
        const ushort* Kc = Ks[cur];
        const ushort* Vc = Vs[cur];

        if (kt < qt) {
            ushort* Kn = (ushort*)Ks[cur ^ 1];
            ushort* Vn = (ushort*)Vs[cur ^ 1];
            #pragma unroll
            for (int t = 0; t < 2; ++t) {
                load_lds16(kg[t], &Kn[(w * 2 + t) * 512]);
                load_lds16(vg[t], &Vn[(w * 2 + t) * 512]);
                kg[t] += 64 * 64;
                vg[t] += 64;
            }
        }

        // ---- S^T = K Q^T ----
        floatx4 s_acc[4];
        #pragma unroll
        for (int kb = 0; kb < 4; ++kb) {
            short8 k0f = *(const short8*)&Kc[(kb * 2 + 0) * 512 + lane * 8];
            short8 k1f = *(const short8*)&Kc[(kb * 2 + 1) * 512 + lane * 8];
            floatx4 z = (floatx4){0.f, 0.f, 0.f, 0.f};
            z = __builtin_amdgcn_mfma_f32_16x16x32_bf16(k0f, a0, z, 0, 0, 0);
            z = __builtin_amdgcn_mfma_f32_16x16x32_bf16(k1f, a1, z, 0, 0, 0);
            s_acc[kb] = z;
        }

        // ---- p = exp(s/8); write P rows ----
        if (kt == qt) {
            #pragma unroll
            for (int kb = 0; kb < 4; ++kb) {
                const int kbase = kb * 16 + quad * 4;
                float p[4];
                #pragma unroll
                for (int r = 0; r < 4; ++r) {
                    float e = __expf(s_acc[kb][r] * 0.125f);
                    p[r] = (kbase + r > myq) ? 0.f : e;
                    l_lane += p[r];
                }
                uint2 u = { bfpack2(p[0], p[1]), bfpack2(p[2], p[3]) };
                *(uint2*)&Ps[myq * LP + kbase] = u;
            }
        } else {
            #pragma unroll
            for (int kb = 0; kb < 4; ++kb) {
                const int kbase = kb * 16 + quad * 4;
                float p[4];
                #pragma unroll
                for (int r = 0; r < 4; ++r) {
                    p[r] = __expf(s_acc[kb][r] * 0.125f);
                    l_lane += p[r];
                }
                uint2 u = { bfpack2(p[0], p[1]), bfpack2(p[2], p[3]) };
                *(uint2*)&Ps[myq * LP + kbase] = u;
            }
        }

        // ---- O += P V ----
        short8 pa0 = *(const short8*)&Ps[(w * 16 + col) * LP + quad * 8];
        short8 pa1 = *(const short8*)&Ps[(w * 16 + col) * LP + 32 + quad * 8];
        #pragma unroll
        for (int dbi = 0; dbi < 4; ++dbi) {
            short8 vb0 = *(const short8*)&Vc[(dbi * 2 + 0) * 512 + lane * 8];
            short8 vb1 = *(const short8*)&Vc[(dbi * 2 + 1) * 512 + lane * 8];
            acc_o[dbi] = __builtin_amdgcn_mfma_f32_16x16x32_bf16(pa0, vb0, acc_o[dbi], 0, 0, 0);
            acc_o[dbi] = __builtin_amdgcn_mfma_f32_16x16x32_bf16(pa1, vb1, acc_o[dbi], 0, 0, 0);
        }

        __syncthreads();
    }

    // ---- finalize l ----
    l_lane += __shfl_xor(l_lane, 16);
    l_lane += __shfl_xor(l_lane, 32);
    if (quad == 0) ls[w][col] = 1.f / l_lane;
    float4 invv = *(const float4*)&ls[w][quad * 4];

    #pragma unroll
    for (int dbi = 0; dbi < 4; ++dbi)
        #pragma unroll
        for (int r = 0; r < 4; ++r) {
            int q = q0 + w * 16 + quad * 4 + r;
            int d = dbi * 16 + col;
            float inv = (r == 0) ? invv.x : (r == 1) ? invv.y : (r == 2) ? invv.z : invv.w;
            out[((size_t)(b * SEQ + q)) * EMBED_DIM + h * 64 + d] = f2bf(acc_o[dbi][r] * inv);
        }
}

// ---------------------------------------------------------------------------
extern "C" void kernel_launch(void* const* d_in, const int* in_sizes, int n_in,
                              void* d_out, int out_size, void* d_ws, size_t ws_size,
                              hipStream_t stream)
{
    const float* x     = (const float*)d_in[0];
    const float* W_qkv = (const float*)d_in[1];
    const float* b_qkv = (const float*)d_in[2];
    const float* W_out = (const float*)d_in[3];
    const float* b_out = (const float*)d_in[4];
    float* out = (float*)d_out;

    const int M  = BATCH * SEQ;            // 4096
    const int D  = EMBED_DIM;              // 1024
    const int N1 = 3 * D;                  // 3072
    const size_t HE = (size_t)BATCH * NUM_HEADS * SEQ * 64;  // 4M

    ushort* xb    = (ushort*)d_ws;
    ushort* Wqb_t = xb + (size_t)M * D;
    ushort* Wob_t = Wqb_t + (size_t)D * N1;
    ushort* Qb    = Wob_t + (size_t)D * D;
    ushort* Kb    = Qb + HE;
    ushort* Vt    = Kb + HE;
    ushort* attnb = Vt + HE;

    // 0) fused prep: cast x, transpose+cast weights
    prep_all<<<5120, 256, 0, stream>>>(x, W_qkv, W_out, xb, Wqb_t, Wob_t);

    // 1) qkv projection — 256^2 8-phase, 192 blocks x 512 threads
    gemm_qkv_8ph<<<dim3(192), 512, 0, stream>>>(xb, Wqb_t, b_qkv, Qb, Kb, Vt);

    // 2) flash attention
    attn_fused<<<dim3(32 * 32), 256, 0, stream>>>(Qb, Kb, Vt, attnb);

    // 3) output projection
    gemm_out_mfma<<<dim3(D / 128, M / 128), 256, 0, stream>>>(
        attnb, Wob_t, b_out, out);
}

// Round 2
// 207.705 us; speedup vs baseline: 1.0047x; 1.0047x over previous
//
#include <hip/hip_runtime.h>
#include <hip/hip_bf16.h>
#include <math.h>

#define EMBED_DIM 1024
#define NUM_HEADS 16
#define HEAD_DIM 64
#define BATCH 2
#define SEQ 2048

using short8  = __attribute__((ext_vector_type(8))) short;
using floatx4 = __attribute__((ext_vector_type(4))) float;

__device__ __forceinline__ ushort f2bf(float f) {
    unsigned u = __float_as_uint(f);
    u = (u + 0x7FFFu + ((u >> 16) & 1u)) >> 16;   // RNE
    return (ushort)u;
}

// pack two floats to bf16x2 (half-up rounding — P values are in [0,1], fine)
__device__ __forceinline__ unsigned bfpack2(float a, float b) {
    return ((__float_as_uint(a) + 0x8000u) >> 16) |
           (((__float_as_uint(b) + 0x8000u) >> 16) << 16);
}

// async global->LDS, 16B per lane; LDS dest = wave-uniform base + lane*16.
__device__ __forceinline__ void load_lds16(const ushort* g, ushort* l) {
    __builtin_amdgcn_global_load_lds(
        (const __attribute__((address_space(1))) void*)g,
        (__attribute__((address_space(3))) void*)l, 16, 0, 0);
}

// ---------------------------------------------------------------------------
// Fused prep: cast x -> bf16, transpose+cast W_qkv and W_out.
// ---------------------------------------------------------------------------
__device__ __forceinline__ void tc_tile(
    const float* __restrict__ W, ushort* __restrict__ Wt,
    int K, int N, int n0, int k0, float (*t)[65])
{
    const int c = threadIdx.x & 63, r0 = (threadIdx.x >> 6) * 16;
    #pragma unroll
    for (int r = 0; r < 16; ++r)
        t[r0 + r][c] = W[(size_t)(k0 + r0 + r) * N + n0 + c];
    __syncthreads();
    #pragma unroll
    for (int r = 0; r < 16; ++r)
        Wt[(size_t)(n0 + r0 + r) * K + k0 + c] = f2bf(t[c][r0 + r]);
}

__global__ __launch_bounds__(256) void prep_all(
    const float* __restrict__ x, const float* __restrict__ W_qkv,
    const float* __restrict__ W_out,
    ushort* __restrict__ xb, ushort* __restrict__ Wqb_t, ushort* __restrict__ Wob_t)
{
    __shared__ float t[64][65];
    const int bx = blockIdx.x;
    if (bx < 4096) {
        int i = (bx * 256 + threadIdx.x) * 4;
        float4 v = *(const float4*)&x[i];
        ushort4 o = { f2bf(v.x), f2bf(v.y), f2bf(v.z), f2bf(v.w) };
        *(ushort4*)&xb[i] = o;
    } else if (bx < 4096 + 768) {
        int b = bx - 4096;
        tc_tile(W_qkv, Wqb_t, 1024, 3072, (b % 48) * 64, (b / 48) * 64, t);
    } else {
        int b = bx - 4864;
        tc_tile(W_out, Wob_t, 1024, 1024, (b % 16) * 64, (b / 16) * 64, t);
    }
}

// ---------------------------------------------------------------------------
// Old 128x128 double-buffered core — still used by gemm_out.
// ---------------------------------------------------------------------------
#define GK 1024

__device__ __forceinline__ void gemm_core(
    const ushort* __restrict__ A, const ushort* __restrict__ Bt,
    int m0, int n0, ushort* As0, ushort* As1, ushort* Bs0, ushort* Bs1,
    floatx4 acc[4][4])
{
    const int tid  = threadIdx.x;
    const int w    = tid >> 6;
    const int lane = tid & 63;
    const int col  = lane & 15;
    const int quad = lane >> 4;
    const int wm   = w >> 1, wn = w & 1;

    #pragma unroll
    for (int i = 0; i < 4; ++i)
        #pragma unroll
        for (int j = 0; j < 4; ++j)
            acc[i][j] = (floatx4){0.f, 0.f, 0.f, 0.f};

    const int o0   = w * 2048 + lane * 16;
    const int row0 = o0 >> 6;
    const int ke0  = (o0 & 63) >> 1;
    const int loff = (w * 2048) >> 1;

    const ushort* ga = A  + (size_t)(m0 + row0) * GK + ke0;
    const ushort* gb = Bt + (size_t)(n0 + row0) * GK + ke0;

    #pragma unroll
    for (int t = 0; t < 2; ++t) {
        load_lds16(ga + (size_t)t * 16 * GK, As0 + loff + t * 512);
        load_lds16(gb + (size_t)t * 16 * GK, Bs0 + loff + t * 512);
    }
    __syncthreads();

    for (int k0 = 0; k0 < GK; k0 += 32) {
        const int cur = (k0 >> 5) & 1;
        ushort* Ac = cur ? As1 : As0;
        ushort* Bc = cur ? Bs1 : Bs0;
        ushort* An = cur ? As0 : As1;
        ushort* Bn = cur ? Bs0 : Bs1;

        if (k0 + 32 < GK) {
            #pragma unroll
            for (int t = 0; t < 2; ++t) {
                load_lds16(ga + (k0 + 32) + (size_t)t * 16 * GK, An + loff + t * 512);
                load_lds16(gb + (k0 + 32) + (size_t)t * 16 * GK, Bn + loff + t * 512);
            }
        }

        short8 af[4], bf[4];
        #pragma unroll
        for (int i = 0; i < 4; ++i)
            af[i] = *(const short8*)&Ac[(wm * 64 + i * 16 + col) * 32 + quad * 8];
        #pragma unroll
        for (int j = 0; j < 4; ++j)
            bf[j] = *(const short8*)&Bc[(wn * 64 + j * 16 + col) * 32 + quad * 8];
        #pragma unroll
        for (int i = 0; i < 4; ++i)
            #pragma unroll
            for (int j = 0; j < 4; ++j)
                acc[i][j] = __builtin_amdgcn_mfma_f32_16x16x32_bf16(af[i], bf[j], acc[i][j], 0, 0, 0);

        __syncthreads();
    }
}

// ---------------------------------------------------------------------------
// qkv projection: 256^2 8-phase schedule, v2.
//   Fixes vs v1 (which ran 3x above the structural floor):
//   (1) m201-exact staging stream: ONE half-tile per phase with a 4-phase
//       lead — during tile t: [P1: Bh1(t+1)] [P2: Ah0(t+2)] [P3: Bh0(t+2)]
//       [P4: Ah1(t+2)]; single vmcnt(6) per tile at P4 (drains exactly the
//       oldest half-tile, keeps 3 half-tiles = 6 loads in flight).
//       Overwrite safety: each region's overwriting stage issues >=1 phase
//       after the barrier that follows its last read; reads are drained by
//       the per-phase lgkmcnt(0) before that barrier.
//   (2) #pragma unroll 1 outer loop over 2 K-tiles; template<CURB> body so
//       LDS buffer bases are compile-time (ds_read immediates, small I$).
//   (3) sched_barrier(0) after each lgkmcnt(0) pins MFMAs inside their phase
//       (acc quadrants are disjoint across phases, nothing else orders them).
// ---------------------------------------------------------------------------
#define NKT 16            // K / 64
#define TILE_U 16384      // ushorts per 256x64 tile

#define MFMA_BF16(a, b, c) \
    (c) = __builtin_amdgcn_mfma_f32_16x16x32_bf16((a), (b), (c), 0, 0, 0)

#define STAGE(GBASE, LDSARR, BUF, KT, H) do {                                  \
    const ushort* _g = (GBASE) + (size_t)(H) * 128 * GK + (size_t)(KT) * 64;   \
    ushort* _l = (LDSARR) + (BUF) * TILE_U + (H) * 8192 + w * 512;             \
    load_lds16(_g + so0, _l);                                                  \
    load_lds16(_g + so1, _l + 4096);                                           \
} while (0)

template<int CURB>
__device__ __forceinline__ void tile_body(
    ushort* As, ushort* Bs, const ushort* gA, const ushort* gB,
    size_t so0, size_t so1, int w, int arow, int brow, int kb0, int kb1,
    floatx4 (*acc)[4], int T, bool pfB1, bool pf2)
{
    const ushort* Ab = As + CURB * TILE_U;
    const ushort* Bb = Bs + CURB * TILE_U;
    short8 af0[4][2], af1[4][2], bf0[2][2], bf1[2][2];

    // ---- P1: read A-h0 (8) + B-h0 (4); stage Bh1(T+1) -> buf CURB^1 ----
    #pragma unroll
    for (int i = 0; i < 4; ++i) {
        af0[i][0] = *(const short8*)&Ab[arow + i * 1024 + kb0];
        af0[i][1] = *(const short8*)&Ab[arow + i * 1024 + kb1];
    }
    #pragma unroll
    for (int j = 0; j < 2; ++j) {
        bf0[j][0] = *(const short8*)&Bb[brow + j * 1024 + kb0];
        bf0[j][1] = *(const short8*)&Bb[brow + j * 1024 + kb1];
    }
    if (pfB1) STAGE(gB, Bs, CURB ^ 1, T + 1, 1);
    __builtin_amdgcn_s_barrier();
    asm volatile("s_waitcnt lgkmcnt(0)" ::: "memory");
    __builtin_amdgcn_sched_barrier(0);
    __builtin_amdgcn_s_setprio(1);
    #pragma unroll
    for (int i = 0; i < 4; ++i)
        #pragma unroll
        for (int j = 0; j < 2; ++j) {
            MFMA_BF16(af0[i][0], bf0[j][0], acc[i][j]);
            MFMA_BF16(af0[i][1], bf0[j][1], acc[i][j]);
        }
    __builtin_amdgcn_s_setprio(0);
    __builtin_amdgcn_s_barrier();

    // ---- P2: read A-h1 (8); stage Ah0(T+2) -> buf CURB ----
    #pragma unroll
    for (int i = 0; i < 4; ++i) {
        af1[i][0] = *(const short8*)&Ab[arow + 4096 + i * 1024 + kb0];
        af1[i][1] = *(const short8*)&Ab[arow + 4096 + i * 1024 + kb1];
    }
    if (pf2) STAGE(gA, As, CURB, T + 2, 0);
    __builtin_amdgcn_s_barrier();
    asm volatile("s_waitcnt lgkmcnt(0)" ::: "memory");
    __builtin_amdgcn_sched_barrier(0);
    __builtin_amdgcn_s_setprio(1);
    #pragma unroll
    for (int i = 0; i < 4; ++i)
        #pragma unroll
        for (int j = 0; j < 2; ++j) {
            MFMA_BF16(af1[i][0], bf0[j][0], acc[4 + i][j]);
            MFMA_BF16(af1[i][1], bf0[j][1], acc[4 + i][j]);
        }
    __builtin_amdgcn_s_setprio(0);
    __builtin_amdgcn_s_barrier();

    // ---- P3: read B-h1 (4); stage Bh0(T+2) -> buf CURB ----
    #pragma unroll
    for (int j = 0; j < 2; ++j) {
        bf1[j][0] = *(const short8*)&Bb[brow + 2048 + j * 1024 + kb0];
        bf1[j][1] = *(const short8*)&Bb[brow + 2048 + j * 1024 + kb1];
    }
    if (pf2) STAGE(gB, Bs, CURB, T + 2, 0);
    __builtin_amdgcn_s_barrier();
    asm volatile("s_waitcnt lgkmcnt(0)" ::: "memory");
    __builtin_amdgcn_sched_barrier(0);
    __builtin_amdgcn_s_setprio(1);
    #pragma unroll
    for (int i = 0; i < 4; ++i)
        #pragma unroll
        for (int j = 0; j < 2; ++j) {
            MFMA_BF16(af1[i][0], bf1[j][0], acc[4 + i][2 + j]);
            MFMA_BF16(af1[i][1], bf1[j][1], acc[4 + i][2 + j]);
        }
    __builtin_amdgcn_s_setprio(0);
    __builtin_amdgcn_s_barrier();

    // ---- P4: no reads (af0/bf1 live); stage Ah1(T+2); counted wait ----
    if (pf2) STAGE(gA, As, CURB, T + 2, 1);
    __builtin_amdgcn_s_barrier();
    __builtin_amdgcn_s_setprio(1);
    #pragma unroll
    for (int i = 0; i < 4; ++i)
        #pragma unroll
        for (int j = 0; j < 2; ++j) {
            MFMA_BF16(af0[i][0], bf1[j][0], acc[i][2 + j]);
            MFMA_BF16(af0[i][1], bf1[j][1], acc[i][2 + j]);
        }
    __builtin_amdgcn_s_setprio(0);
    if (pf2) asm volatile("s_waitcnt vmcnt(6)" ::: "memory");
    else     asm volatile("s_waitcnt vmcnt(0)" ::: "memory");
    __builtin_amdgcn_s_barrier();
}

__global__ __launch_bounds__(512, 2) void gemm_qkv_8ph(
    const ushort* __restrict__ A, const ushort* __restrict__ Bt,
    const float* __restrict__ bias,
    ushort* __restrict__ Qb, ushort* __restrict__ Kb, ushort* __restrict__ Vt)
{
    __shared__ __align__(16) ushort As[2 * TILE_U];   // 64 KiB
    __shared__ __align__(16) ushort Bs[2 * TILE_U];   // 64 KiB

    // T1: bijective XCD swizzle, 192 blocks = 8 XCDs x 24
    const int bid = blockIdx.x;
    const int swz = (bid & 7) * 24 + (bid >> 3);
    const int bx = swz % 12, by = swz / 12;
    const int n0 = bx * 256, m0 = by * 256;

    const int tid  = threadIdx.x;
    const int w    = tid >> 6;
    const int lane = tid & 63;
    const int col  = lane & 15;
    const int quad = lane >> 4;
    const int wm   = w >> 2, wn = w & 3;

    // staging: per-lane pre-swizzled global offsets (ushort units)
    // linear LDS byte y holds logical byte y ^ ((row&7)<<4), row = y>>7
    const int srow = w * 8 + (lane >> 3);
    const int scx  = ((lane & 7) ^ (lane >> 3)) << 3;          // ushorts
    const size_t so0 = (size_t)srow * GK + scx;
    const size_t so1 = so0 + (size_t)64 * GK;

    const ushort* gA = A  + (size_t)m0 * GK;
    const ushort* gB = Bt + (size_t)n0 * GK;

    // T2: swizzled ds_read k-offsets (ushort units) — same XOR involution
    const int kb0 = (quad * 8) ^ ((col & 7) << 3);             // kk = 0
    const int kb1 = (32 + quad * 8) ^ ((col & 7) << 3);        // kk = 1
    const int arow = (wm * 128 + col) * 64;
    const int brow = (wn * 64 + col) * 64;

    floatx4 acc[8][4];
    #pragma unroll
    for (int i = 0; i < 8; ++i)
        #pragma unroll
        for (int j = 0; j < 4; ++j)
            acc[i][j] = (floatx4){0.f, 0.f, 0.f, 0.f};

    // prologue: tile0 (4 halves) + tile1's first 3 halves; drain tile0,
    // keep 3 half-tiles (6 loads) in flight — the steady-state invariant.
    STAGE(gA, As, 0, 0, 0);   // Ah0(0)
    STAGE(gB, Bs, 0, 0, 0);   // Bh0(0)
    STAGE(gA, As, 0, 0, 1);   // Ah1(0)
    STAGE(gB, Bs, 0, 0, 1);   // Bh1(0)
    STAGE(gA, As, 1, 1, 0);   // Ah0(1)
    STAGE(gB, Bs, 1, 1, 0);   // Bh0(1)
    STAGE(gA, As, 1, 1, 1);   // Ah1(1)
    asm volatile("s_waitcnt vmcnt(6)" ::: "memory");
    __builtin_amdgcn_s_barrier();

    #pragma unroll 1
    for (int tt = 0; tt < NKT; tt += 2) {
        const bool pf2 = (tt < NKT - 2);
        tile_body<0>(As, Bs, gA, gB, so0, so1, w, arow, brow, kb0, kb1,
                     acc, tt, true, pf2);
        tile_body<1>(As, Bs, gA, gB, so0, so1, w, arow, brow, kb0, kb1,
                     acc, tt + 1, pf2, pf2);
    }

    // ---- epilogue: bias + split/cast Q,K,V (V transposed) ----
    #pragma unroll
    for (int j = 0; j < 4; ++j) {
        const int n = n0 + wn * 64 + j * 16 + col;
        const float bj = bias[n];
        const int part = n >> 10;
        const int h = (n >> 6) & 15;
        const int d = n & 63;
        #pragma unroll
        for (int i = 0; i < 8; ++i)
            #pragma unroll
            for (int r = 0; r < 4; ++r) {
                const int m = m0 + wm * 128 + i * 16 + quad * 4 + r;
                const int b = m >> 11, s = m & 2047;
                const int bh = b * 16 + h;
                const ushort bv = f2bf(acc[i][j][r] + bj);
                if (part == 0)      Qb[((size_t)bh * SEQ + s) * 64 + d] = bv;
                else if (part == 1) Kb[((size_t)bh * SEQ + s) * 64 + d] = bv;
                else                Vt[((size_t)bh * 64 + d) * SEQ + s] = bv;
            }
    }
}

// GEMM2: out = attn_b @ W_out + b_out -> fp32 (old core)
__global__ __launch_bounds__(256) void gemm_out_mfma(
    const ushort* __restrict__ A, const ushort* __restrict__ Bt,
    const float* __restrict__ bias, float* __restrict__ out)
{
    __shared__ __align__(16) ushort As[2][128 * 32];
    __shared__ __align__(16) ushort Bs[2][128 * 32];
    const int n0 = blockIdx.x * 128;
    const int m0 = blockIdx.y * 128;

    floatx4 acc[4][4];
    gemm_core(A, Bt, m0, n0, As[0], As[1], Bs[0], Bs[1], acc);

    const int lane = threadIdx.x & 63;
    const int w    = threadIdx.x >> 6;
    const int col  = lane & 15, quad = lane >> 4;
    const int wm   = w >> 1, wn = w & 1;

    #pragma unroll
    for (int j = 0; j < 4; ++j) {
        const int n = n0 + wn * 64 + j * 16 + col;
        const float bj = bias[n];
        #pragma unroll
        for (int i = 0; i < 4; ++i)
            #pragma unroll
            for (int r = 0; r < 4; ++r) {
                const int m = m0 + wm * 64 + i * 16 + quad * 4 + r;
                out[(size_t)m * EMBED_DIM + n] = acc[i][j][r] + bj;
            }
    }
}

// ---------------------------------------------------------------------------
// Flash attention, bf16 MFMA, fragment-ordered async staging, S^T softmax,
// double-buffered K/V with issue-early prefetch (1 barrier per key-tile).
// ---------------------------------------------------------------------------
#define LP 72

__global__ __launch_bounds__(256) void attn_fused(
    const ushort* __restrict__ Qb, const ushort* __restrict__ Kb,
    const ushort* __restrict__ Vt, ushort* __restrict__ out)
{
    const int id = blockIdx.x;
    const int qt = 31 - (id >> 5);          // reversed: long blocks first (LPT)
    const int bh = id & 31;
    const int b  = bh >> 4, h = bh & 15;
    const int q0 = qt * 64;

    __shared__ __align__(16) ushort Qs[8 * 512];        // 8 KB fragment order
    __shared__ __align__(16) ushort Ks[2][8 * 512];     // 16 KB dbuf
    __shared__ __align__(16) ushort Vs[2][8 * 512];     // 16 KB dbuf
    __shared__ __align__(16) ushort Ps[64 * LP];        // 9 KB
    __shared__ __align__(16) float  ls[4][16];

    const int tid  = threadIdx.x;
    const int w    = tid >> 6;
    const int lane = tid & 63;
    const int col  = lane & 15;
    const int quad = lane >> 4;

    const ushort* kg[2];
    const ushort* vg[2];
    #pragma unroll
    for (int t = 0; t < 2; ++t) {
        kg[t] = Kb + (size_t)bh * SEQ * 64 + (size_t)(w * 16 + col) * 64 + t * 32 + quad * 8;
        vg[t] = Vt + (size_t)bh * 64 * SEQ + (size_t)(w * 16 + col) * SEQ + t * 32 + quad * 8;
    }

    {
        const ushort* Qg = Qb + ((size_t)bh * SEQ + q0) * 64;
        #pragma unroll
        for (int t = 0; t < 2; ++t) {
            load_lds16(Qg + (size_t)(w * 16 + col) * 64 + t * 32 + quad * 8,
                       &Qs[(w * 2 + t) * 512]);
            load_lds16(kg[t], &Ks[0][(w * 2 + t) * 512]);
            load_lds16(vg[t], &Vs[0][(w * 2 + t) * 512]);
            kg[t] += 64 * 64;   // -> tile 1
            vg[t] += 64;
        }
    }
    __syncthreads();

    const short8 a0 = *(const short8*)&Qs[(w * 2 + 0) * 512 + lane * 8];
    const short8 a1 = *(const short8*)&Qs[(w * 2 + 1) * 512 + lane * 8];

    floatx4 acc_o[4];
    #pragma unroll
    for (int dbi = 0; dbi < 4; ++dbi) acc_o[dbi] = (floatx4){0.f, 0.f, 0.f, 0.f};
    float l_lane = 0.f;
    const int myq = w * 16 + col;

    for (int kt = 0; kt <= qt; ++kt) {
        const int cur = kt & 1;
        const ushort* Kc = Ks[cur];
        const ushort* Vc = Vs[cur];

        if (kt < qt) {
            ushort* Kn = (ushort*)Ks[cur ^ 1];
            ushort* Vn = (ushort*)Vs[cur ^ 1];
            #pragma unroll
            for (int t = 0; t < 2; ++t) {
                load_lds16(kg[t], &Kn[(w * 2 + t) * 512]);
                load_lds16(vg[t], &Vn[(w * 2 + t) * 512]);
                kg[t] += 64 * 64;
                vg[t] += 64;
            }
        }

        // ---- S^T = K Q^T ----
        floatx4 s_acc[4];
        #pragma unroll
        for (int kb = 0; kb < 4; ++kb) {
            short8 k0f = *(const short8*)&Kc[(kb * 2 + 0) * 512 + lane * 8];
            short8 k1f = *(const short8*)&Kc[(kb * 2 + 1) * 512 + lane * 8];
            floatx4 z = (floatx4){0.f, 0.f, 0.f, 0.f};
            z = __builtin_amdgcn_mfma_f32_16x16x32_bf16(k0f, a0, z, 0, 0, 0);
            z = __builtin_amdgcn_mfma_f32_16x16x32_bf16(k1f, a1, z, 0, 0, 0);
            s_acc[kb] = z;
        }

        // ---- p = exp(s/8); write P rows ----
        if (kt == qt) {
            #pragma unroll
            for (int kb = 0; kb < 4; ++kb) {
                const int kbase = kb * 16 + quad * 4;
                float p[4];
                #pragma unroll
                for (int r = 0; r < 4; ++r) {
                    float e = __expf(s_acc[kb][r] * 0.125f);
                    p[r] = (kbase + r > myq) ? 0.f : e;
                    l_lane += p[r];
                }
                uint2 u = { bfpack2(p[0], p[1]), bfpack2(p[2], p[3]) };
                *(uint2*)&Ps[myq * LP + kbase] = u;
            }
        } else {
            #pragma unroll
            for (int kb = 0; kb < 4; ++kb) {
                const int kbase = kb * 16 + quad * 4;
                float p[4];
                #pragma unroll
                for (int r = 0; r < 4; ++r) {
                    p[r] = __expf(s_acc[kb][r] * 0.125f);
                    l_lane += p[r];
                }
                uint2 u = { bfpack2(p[0], p[1]), bfpack2(p[2], p[3]) };
                *(uint2*)&Ps[myq * LP + kbase] = u;
            }
        }

        // ---- O += P V ----
        short8 pa0 = *(const short8*)&Ps[(w * 16 + col) * LP + quad * 8];
        short8 pa1 = *(const short8*)&Ps[(w * 16 + col) * LP + 32 + quad * 8];
        #pragma unroll
        for (int dbi = 0; dbi < 4; ++dbi) {
            short8 vb0 = *(const short8*)&Vc[(dbi * 2 + 0) * 512 + lane * 8];
            short8 vb1 = *(const short8*)&Vc[(dbi * 2 + 1) * 512 + lane * 8];
            acc_o[dbi] = __builtin_amdgcn_mfma_f32_16x16x32_bf16(pa0, vb0, acc_o[dbi], 0, 0, 0);
            acc_o[dbi] = __builtin_amdgcn_mfma_f32_16x16x32_bf16(pa1, vb1, acc_o[dbi], 0, 0, 0);
        }

        __syncthreads();
    }

    // ---- finalize l ----
    l_lane += __shfl_xor(l_lane, 16);
    l_lane += __shfl_xor(l_lane, 32);
    if (quad == 0) ls[w][col] = 1.f / l_lane;
    float4 invv = *(const float4*)&ls[w][quad * 4];

    #pragma unroll
    for (int dbi = 0; dbi < 4; ++dbi)
        #pragma unroll
        for (int r = 0; r < 4; ++r) {
            int q = q0 + w * 16 + quad * 4 + r;
            int d = dbi * 16 + col;
            float inv = (r == 0) ? invv.x : (r == 1) ? invv.y : (r == 2) ? invv.z : invv.w;
            out[((size_t)(b * SEQ + q)) * EMBED_DIM + h * 64 + d] = f2bf(acc_o[dbi][r] * inv);
        }
}

// ---------------------------------------------------------------------------
extern "C" void kernel_launch(void* const* d_in, const int* in_sizes, int n_in,
                              void* d_out, int out_size, void* d_ws, size_t ws_size,
                              hipStream_t stream)
{
    const float* x     = (const float*)d_in[0];
    const float* W_qkv = (const float*)d_in[1];
    const float* b_qkv = (const float*)d_in[2];
    const float* W_out = (const float*)d_in[3];
    const float* b_out = (const float*)d_in[4];
    float* out = (float*)d_out;

    const int M  = BATCH * SEQ;            // 4096
    const int D  = EMBED_DIM;              // 1024
    const int N1 = 3 * D;                  // 3072
    const size_t HE = (size_t)BATCH * NUM_HEADS * SEQ * 64;  // 4M

    ushort* xb    = (ushort*)d_ws;
    ushort* Wqb_t = xb + (size_t)M * D;
    ushort* Wob_t = Wqb_t + (size_t)D * N1;
    ushort* Qb    = Wob_t + (size_t)D * D;
    ushort* Kb    = Qb + HE;
    ushort* Vt    = Kb + HE;
    ushort* attnb = Vt + HE;

    // 0) fused prep: cast x, transpose+cast weights
    prep_all<<<5120, 256, 0, stream>>>(x, W_qkv, W_out, xb, Wqb_t, Wob_t);

    // 1) qkv projection — 256^2 8-phase v2, 192 blocks x 512 threads
    gemm_qkv_8ph<<<dim3(192), 512, 0, stream>>>(xb, Wqb_t, b_qkv, Qb, Kb, Vt);

    // 2) flash attention
    attn_fused<<<dim3(32 * 32), 256, 0, stream>>>(Qb, Kb, Vt, attnb);

    // 3) output projection
    gemm_out_mfma<<<dim3(D / 128, M / 128), 256, 0, stream>>>(
        attnb, Wob_t, b_out, out);
}

// Round 3
// 204.828 us; speedup vs baseline: 1.0188x; 1.0140x over previous
//
#include <hip/hip_runtime.h>
#include <hip/hip_bf16.h>
#include <math.h>

#define EMBED_DIM 1024
#define NUM_HEADS 16
#define HEAD_DIM 64
#define BATCH 2
#define SEQ 2048

using short8  = __attribute__((ext_vector_type(8))) short;
using floatx4 = __attribute__((ext_vector_type(4))) float;

__device__ __forceinline__ ushort f2bf(float f) {
    unsigned u = __float_as_uint(f);
    u = (u + 0x7FFFu + ((u >> 16) & 1u)) >> 16;   // RNE
    return (ushort)u;
}

__device__ __forceinline__ unsigned bfpack2(float a, float b) {
    return ((__float_as_uint(a) + 0x8000u) >> 16) |
           (((__float_as_uint(b) + 0x8000u) >> 16) << 16);
}

// async global->LDS, 16B per lane; LDS dest = wave-uniform base + lane*16.
__device__ __forceinline__ void load_lds16(const ushort* g, ushort* l) {
    __builtin_amdgcn_global_load_lds(
        (const __attribute__((address_space(1))) void*)g,
        (__attribute__((address_space(3))) void*)l, 16, 0, 0);
}

// byte offset of a __shared__ object within LDS (as(3) numeric value)
__device__ __forceinline__ unsigned lds_addr(const void* p) {
    return (unsigned)(unsigned long long)
        (const __attribute__((address_space(3))) void*)p;
}

// opaque LDS read: invisible to the compiler's waitcnt pass, so no
// conservative vmcnt(0)-vs-DMA waits get inserted. Manual lgkmcnt required.
#define DSR(dst, addr, OFF) do { floatx4 _t;                                   \
    asm volatile("ds_read_b128 %0, %1 offset:" OFF                             \
                 : "=v"(_t) : "v"(addr));                                      \
    (dst) = __builtin_bit_cast(short8, _t); } while (0)

// ---------------------------------------------------------------------------
// Fused prep: cast x -> bf16, transpose+cast W_qkv and W_out.
// ---------------------------------------------------------------------------
__device__ __forceinline__ void tc_tile(
    const float* __restrict__ W, ushort* __restrict__ Wt,
    int K, int N, int n0, int k0, float (*t)[65])
{
    const int c = threadIdx.x & 63, r0 = (threadIdx.x >> 6) * 16;
    #pragma unroll
    for (int r = 0; r < 16; ++r)
        t[r0 + r][c] = W[(size_t)(k0 + r0 + r) * N + n0 + c];
    __syncthreads();
    #pragma unroll
    for (int r = 0; r < 16; ++r)
        Wt[(size_t)(n0 + r0 + r) * K + k0 + c] = f2bf(t[c][r0 + r]);
}

__global__ __launch_bounds__(256) void prep_all(
    const float* __restrict__ x, const float* __restrict__ W_qkv,
    const float* __restrict__ W_out,
    ushort* __restrict__ xb, ushort* __restrict__ Wqb_t, ushort* __restrict__ Wob_t)
{
    __shared__ float t[64][65];
    const int bx = blockIdx.x;
    if (bx < 4096) {
        int i = (bx * 256 + threadIdx.x) * 4;
        float4 v = *(const float4*)&x[i];
        ushort4 o = { f2bf(v.x), f2bf(v.y), f2bf(v.z), f2bf(v.w) };
        *(ushort4*)&xb[i] = o;
    } else if (bx < 4096 + 768) {
        int b = bx - 4096;
        tc_tile(W_qkv, Wqb_t, 1024, 3072, (b % 48) * 64, (b / 48) * 64, t);
    } else {
        int b = bx - 4864;
        tc_tile(W_out, Wob_t, 1024, 1024, (b % 16) * 64, (b / 16) * 64, t);
    }
}

// ---------------------------------------------------------------------------
// Old 128x128 double-buffered core — still used by gemm_out.
// ---------------------------------------------------------------------------
#define GK 1024

__device__ __forceinline__ void gemm_core(
    const ushort* __restrict__ A, const ushort* __restrict__ Bt,
    int m0, int n0, ushort* As0, ushort* As1, ushort* Bs0, ushort* Bs1,
    floatx4 acc[4][4])
{
    const int tid  = threadIdx.x;
    const int w    = tid >> 6;
    const int lane = tid & 63;
    const int col  = lane & 15;
    const int quad = lane >> 4;
    const int wm   = w >> 1, wn = w & 1;

    #pragma unroll
    for (int i = 0; i < 4; ++i)
        #pragma unroll
        for (int j = 0; j < 4; ++j)
            acc[i][j] = (floatx4){0.f, 0.f, 0.f, 0.f};

    const int o0   = w * 2048 + lane * 16;
    const int row0 = o0 >> 6;
    const int ke0  = (o0 & 63) >> 1;
    const int loff = (w * 2048) >> 1;

    const ushort* ga = A  + (size_t)(m0 + row0) * GK + ke0;
    const ushort* gb = Bt + (size_t)(n0 + row0) * GK + ke0;

    #pragma unroll
    for (int t = 0; t < 2; ++t) {
        load_lds16(ga + (size_t)t * 16 * GK, As0 + loff + t * 512);
        load_lds16(gb + (size_t)t * 16 * GK, Bs0 + loff + t * 512);
    }
    __syncthreads();

    for (int k0 = 0; k0 < GK; k0 += 32) {
        const int cur = (k0 >> 5) & 1;
        ushort* Ac = cur ? As1 : As0;
        ushort* Bc = cur ? Bs1 : Bs0;
        ushort* An = cur ? As0 : As1;
        ushort* Bn = cur ? Bs0 : Bs1;

        if (k0 + 32 < GK) {
            #pragma unroll
            for (int t = 0; t < 2; ++t) {
                load_lds16(ga + (k0 + 32) + (size_t)t * 16 * GK, An + loff + t * 512);
                load_lds16(gb + (k0 + 32) + (size_t)t * 16 * GK, Bn + loff + t * 512);
            }
        }

        short8 af[4], bf[4];
        #pragma unroll
        for (int i = 0; i < 4; ++i)
            af[i] = *(const short8*)&Ac[(wm * 64 + i * 16 + col) * 32 + quad * 8];
        #pragma unroll
        for (int j = 0; j < 4; ++j)
            bf[j] = *(const short8*)&Bc[(wn * 64 + j * 16 + col) * 32 + quad * 8];
        #pragma unroll
        for (int i = 0; i < 4; ++i)
            #pragma unroll
            for (int j = 0; j < 4; ++j)
                acc[i][j] = __builtin_amdgcn_mfma_f32_16x16x32_bf16(af[i], bf[j], acc[i][j], 0, 0, 0);

        __syncthreads();
    }
}

// ---------------------------------------------------------------------------
// qkv projection: 256^2 8-phase schedule, v3.
//   v3 change: fragment loads via inline-asm ds_read_b128 (opaque to the
//   compiler's waitcnt pass). Theory: with C++ ds_reads the pass cannot
//   disambiguate them from global_load_lds's LDS writes and inserts
//   conservative vmcnt(0) waits before every phase's reads, serializing the
//   pipeline (v1 == v2 == ~9.5k cyc/tile regardless of our vmcnt schedule).
//   All waits are now manual: per-phase lgkmcnt(0)+sched_barrier(0) (rule
//   #18), one counted vmcnt(6) per K-tile.
//   Stage slots (airtight vs read drains): P1: Bh1(T+1) -> other buf;
//   P3: Ah0(T+2); P4: Ah1(T+2) + Bh0(T+2) -> current buf. Each stage issues
//   only after the barrier that follows the drained last read of its region.
// ---------------------------------------------------------------------------
#define NKT 16            // K / 64
#define TILE_U 16384      // ushorts per 256x64 tile

#define MFMA_BF16(a, b, c) \
    (c) = __builtin_amdgcn_mfma_f32_16x16x32_bf16((a), (b), (c), 0, 0, 0)

#define STAGE(GBASE, LDSARR, BUF, KT, H) do {                                  \
    const ushort* _g = (GBASE) + (size_t)(H) * 128 * GK + (size_t)(KT) * 64;   \
    ushort* _l = (LDSARR) + (BUF) * TILE_U + (H) * 8192 + w * 512;             \
    load_lds16(_g + so0, _l);                                                  \
    load_lds16(_g + so1, _l + 4096);                                           \
} while (0)

template<int CURB>
__device__ __forceinline__ void tile_body(
    unsigned a0, unsigned a1, unsigned b0, unsigned b1,
    ushort* As, ushort* Bs, const ushort* gA, const ushort* gB,
    size_t so0, size_t so1, int w,
    floatx4 (*acc)[4], int T, bool pfB1, bool pf2)
{
    short8 af0[4][2], af1[4][2], bf0[2][2], bf1[2][2];

    // ---- P1: read A-h0 (8) + B-h0 (4); stage Bh1(T+1) -> buf CURB^1 ----
    DSR(af0[0][0], a0, "0");    DSR(af0[0][1], a1, "0");
    DSR(af0[1][0], a0, "2048"); DSR(af0[1][1], a1, "2048");
    DSR(af0[2][0], a0, "4096"); DSR(af0[2][1], a1, "4096");
    DSR(af0[3][0], a0, "6144"); DSR(af0[3][1], a1, "6144");
    DSR(bf0[0][0], b0, "0");    DSR(bf0[0][1], b1, "0");
    DSR(bf0[1][0], b0, "2048"); DSR(bf0[1][1], b1, "2048");
    if (pfB1) STAGE(gB, Bs, CURB ^ 1, T + 1, 1);
    __builtin_amdgcn_s_barrier();
    asm volatile("s_waitcnt lgkmcnt(0)" ::: "memory");
    __builtin_amdgcn_sched_barrier(0);
    __builtin_amdgcn_s_setprio(1);
    #pragma unroll
    for (int i = 0; i < 4; ++i)
        #pragma unroll
        for (int j = 0; j < 2; ++j) {
            MFMA_BF16(af0[i][0], bf0[j][0], acc[i][j]);
            MFMA_BF16(af0[i][1], bf0[j][1], acc[i][j]);
        }
    __builtin_amdgcn_s_setprio(0);
    __builtin_amdgcn_sched_barrier(0);
    __builtin_amdgcn_s_barrier();

    // ---- P2: read A-h1 (8); no stage ----
    DSR(af1[0][0], a0, "8192");  DSR(af1[0][1], a1, "8192");
    DSR(af1[1][0], a0, "10240"); DSR(af1[1][1], a1, "10240");
    DSR(af1[2][0], a0, "12288"); DSR(af1[2][1], a1, "12288");
    DSR(af1[3][0], a0, "14336"); DSR(af1[3][1], a1, "14336");
    __builtin_amdgcn_s_barrier();
    asm volatile("s_waitcnt lgkmcnt(0)" ::: "memory");
    __builtin_amdgcn_sched_barrier(0);
    __builtin_amdgcn_s_setprio(1);
    #pragma unroll
    for (int i = 0; i < 4; ++i)
        #pragma unroll
        for (int j = 0; j < 2; ++j) {
            MFMA_BF16(af1[i][0], bf0[j][0], acc[4 + i][j]);
            MFMA_BF16(af1[i][1], bf0[j][1], acc[4 + i][j]);
        }
    __builtin_amdgcn_s_setprio(0);
    __builtin_amdgcn_sched_barrier(0);
    __builtin_amdgcn_s_barrier();

    // ---- P3: read B-h1 (4); stage Ah0(T+2) -> buf CURB ----
    DSR(bf1[0][0], b0, "4096"); DSR(bf1[0][1], b1, "4096");
    DSR(bf1[1][0], b0, "6144"); DSR(bf1[1][1], b1, "6144");
    if (pf2) STAGE(gA, As, CURB, T + 2, 0);
    __builtin_amdgcn_s_barrier();
    asm volatile("s_waitcnt lgkmcnt(0)" ::: "memory");
    __builtin_amdgcn_sched_barrier(0);
    __builtin_amdgcn_s_setprio(1);
    #pragma unroll
    for (int i = 0; i < 4; ++i)
        #pragma unroll
        for (int j = 0; j < 2; ++j) {
            MFMA_BF16(af1[i][0], bf1[j][0], acc[4 + i][2 + j]);
            MFMA_BF16(af1[i][1], bf1[j][1], acc[4 + i][2 + j]);
        }
    __builtin_amdgcn_s_setprio(0);
    __builtin_amdgcn_sched_barrier(0);
    __builtin_amdgcn_s_barrier();

    // ---- P4: no reads (af0/bf1 live); stage Ah1(T+2)+Bh0(T+2); drain ----
    if (pf2) { STAGE(gA, As, CURB, T + 2, 1); STAGE(gB, Bs, CURB, T + 2, 0); }
    __builtin_amdgcn_s_barrier();
    __builtin_amdgcn_s_setprio(1);
    #pragma unroll
    for (int i = 0; i < 4; ++i)
        #pragma unroll
        for (int j = 0; j < 2; ++j) {
            MFMA_BF16(af0[i][0], bf1[j][0], acc[i][2 + j]);
            MFMA_BF16(af0[i][1], bf1[j][1], acc[i][2 + j]);
        }
    __builtin_amdgcn_s_setprio(0);
    __builtin_amdgcn_sched_barrier(0);
    if (pf2) asm volatile("s_waitcnt vmcnt(6)" ::: "memory");
    else     asm volatile("s_waitcnt vmcnt(0)" ::: "memory");
    __builtin_amdgcn_s_barrier();
}

__global__ __launch_bounds__(512, 2) void gemm_qkv_8ph(
    const ushort* __restrict__ A, const ushort* __restrict__ Bt,
    const float* __restrict__ bias,
    ushort* __restrict__ Qb, ushort* __restrict__ Kb, ushort* __restrict__ Vt)
{
    __shared__ __align__(16) ushort As[2 * TILE_U];   // 64 KiB
    __shared__ __align__(16) ushort Bs[2 * TILE_U];   // 64 KiB

    // T1: bijective XCD swizzle, 192 blocks = 8 XCDs x 24
    const int bid = blockIdx.x;
    const int swz = (bid & 7) * 24 + (bid >> 3);
    const int bx = swz % 12, by = swz / 12;
    const int n0 = bx * 256, m0 = by * 256;

    const int tid  = threadIdx.x;
    const int w    = tid >> 6;
    const int lane = tid & 63;
    const int col  = lane & 15;
    const int quad = lane >> 4;
    const int wm   = w >> 2, wn = w & 3;

    // staging: per-lane pre-swizzled global offsets (ushort units)
    // linear LDS byte y holds logical byte y ^ ((row&7)<<4), row = y>>7
    const int srow = w * 8 + (lane >> 3);
    const int scx  = ((lane & 7) ^ (lane >> 3)) << 3;          // ushorts
    const size_t so0 = (size_t)srow * GK + scx;
    const size_t so1 = so0 + (size_t)64 * GK;

    const ushort* gA = A  + (size_t)m0 * GK;
    const ushort* gB = Bt + (size_t)n0 * GK;

    // T2: swizzled ds_read byte addresses — same XOR involution
    const int kb0 = (quad * 8) ^ ((col & 7) << 3);             // ushorts
    const int kb1 = (32 + quad * 8) ^ ((col & 7) << 3);
    const unsigned ldsA = lds_addr(As);
    const unsigned ldsB = lds_addr(Bs);
    const unsigned aA0 = ldsA + (unsigned)((wm * 128 + col) * 64 + kb0) * 2;
    const unsigned aA1 = ldsA + (unsigned)((wm * 128 + col) * 64 + kb1) * 2;
    const unsigned aB0 = ldsB + (unsigned)((wn * 64 + col) * 64 + kb0) * 2;
    const unsigned aB1 = ldsB + (unsigned)((wn * 64 + col) * 64 + kb1) * 2;

    floatx4 acc[8][4];
    #pragma unroll
    for (int i = 0; i < 8; ++i)
        #pragma unroll
        for (int j = 0; j < 4; ++j)
            acc[i][j] = (floatx4){0.f, 0.f, 0.f, 0.f};

    // prologue: tile0 (4 halves) + tile1's {Ah0, Bh0, Ah1}; drain tile0,
    // keep 3 half-tiles (6 loads) in flight — the steady-state invariant.
    STAGE(gA, As, 0, 0, 0);   // Ah0(0)
    STAGE(gB, Bs, 0, 0, 0);   // Bh0(0)
    STAGE(gA, As, 0, 0, 1);   // Ah1(0)
    STAGE(gB, Bs, 0, 0, 1);   // Bh1(0)
    STAGE(gA, As, 1, 1, 0);   // Ah0(1)
    STAGE(gB, Bs, 1, 1, 0);   // Bh0(1)
    STAGE(gA, As, 1, 1, 1);   // Ah1(1)
    asm volatile("s_waitcnt vmcnt(6)" ::: "memory");
    __builtin_amdgcn_s_barrier();

    #pragma unroll 1
    for (int tt = 0; tt < NKT; tt += 2) {
        const bool pf2 = (tt < NKT - 2);
        tile_body<0>(aA0, aA1, aB0, aB1, As, Bs, gA, gB, so0, so1, w,
                     acc, tt, true, pf2);
        tile_body<1>(aA0 + 32768u, aA1 + 32768u, aB0 + 32768u, aB1 + 32768u,
                     As, Bs, gA, gB, so0, so1, w, acc, tt + 1, pf2, pf2);
    }

    // ---- epilogue: bias + split/cast Q,K,V (V transposed) ----
    #pragma unroll
    for (int j = 0; j < 4; ++j) {
        const int n = n0 + wn * 64 + j * 16 + col;
        const float bj = bias[n];
        const int part = n >> 10;
        const int h = (n >> 6) & 15;
        const int d = n & 63;
        #pragma unroll
        for (int i = 0; i < 8; ++i)
            #pragma unroll
            for (int r = 0; r < 4; ++r) {
                const int m = m0 + wm * 128 + i * 16 + quad * 4 + r;
                const int b = m >> 11, s = m & 2047;
                const int bh = b * 16 + h;
                const ushort bv = f2bf(acc[i][j][r] + bj);
                if (part == 0)      Qb[((size_t)bh * SEQ + s) * 64 + d] = bv;
                else if (part == 1) Kb[((size_t)bh * SEQ + s) * 64 + d] = bv;
                else                Vt[((size_t)bh * 64 + d) * SEQ + s] = bv;
            }
    }
}

// GEMM2: out = attn_b @ W_out + b_out -> fp32 (old core)
__global__ __launch_bounds__(256) void gemm_out_mfma(
    const ushort* __restrict__ A, const ushort* __restrict__ Bt,
    const float* __restrict__ bias, float* __restrict__ out)
{
    __shared__ __align__(16) ushort As[2][128 * 32];
    __shared__ __align__(16) ushort Bs[2][128 * 32];
    const int n0 = blockIdx.x * 128;
    const int m0 = blockIdx.y * 128;

    floatx4 acc[4][4];
    gemm_core(A, Bt, m0, n0, As[0], As[1], Bs[0], Bs[1], acc);

    const int lane = threadIdx.x & 63;
    const int w    = threadIdx.x >> 6;
    const int col  = lane & 15, quad = lane >> 4;
    const int wm   = w >> 1, wn = w & 1;

    #pragma unroll
    for (int j = 0; j < 4; ++j) {
        const int n = n0 + wn * 64 + j * 16 + col;
        const float bj = bias[n];
        #pragma unroll
        for (int i = 0; i < 4; ++i)
            #pragma unroll
            for (int r = 0; r < 4; ++r) {
                const int m = m0 + wm * 64 + i * 16 + quad * 4 + r;
                out[(size_t)m * EMBED_DIM + n] = acc[i][j][r] + bj;
            }
    }
}

// ---------------------------------------------------------------------------
// Flash attention (unchanged this round).
// ---------------------------------------------------------------------------
#define LP 72

__global__ __launch_bounds__(256) void attn_fused(
    const ushort* __restrict__ Qb, const ushort* __restrict__ Kb,
    const ushort* __restrict__ Vt, ushort* __restrict__ out)
{
    const int id = blockIdx.x;
    const int qt = 31 - (id >> 5);          // reversed: long blocks first (LPT)
    const int bh = id & 31;
    const int b  = bh >> 4, h = bh & 15;
    const int q0 = qt * 64;

    __shared__ __align__(16) ushort Qs[8 * 512];
    __shared__ __align__(16) ushort Ks[2][8 * 512];
    __shared__ __align__(16) ushort Vs[2][8 * 512];
    __shared__ __align__(16) ushort Ps[64 * LP];
    __shared__ __align__(16) float  ls[4][16];

    const int tid  = threadIdx.x;
    const int w    = tid >> 6;
    const int lane = tid & 63;
    const int col  = lane & 15;
    const int quad = lane >> 4;

    const ushort* kg[2];
    const ushort* vg[2];
    #pragma unroll
    for (int t = 0; t < 2; ++t) {
        kg[t] = Kb + (size_t)bh * SEQ * 64 + (size_t)(w * 16 + col) * 64 + t * 32 + quad * 8;
        vg[t] = Vt + (size_t)bh * 64 * SEQ + (size_t)(w * 16 + col) * SEQ + t * 32 + quad * 8;
    }

    {
        const ushort* Qg = Qb + ((size_t)bh * SEQ + q0) * 64;
        #pragma unroll
        for (int t = 0; t < 2; ++t) {
            load_lds16(Qg + (size_t)(w * 16 + col) * 64 + t * 32 + quad * 8,
                       &Qs[(w * 2 + t) * 512]);
            load_lds16(kg[t], &Ks[0][(w * 2 + t) * 512]);
            load_lds16(vg[t], &Vs[0][(w * 2 + t) * 512]);
            kg[t] += 64 * 64;   // -> tile 1
            vg[t] += 64;
        }
    }
    __syncthreads();

    const short8 a0 = *(const short8*)&Qs[(w * 2 + 0) * 512 + lane * 8];
    const short8 a1 = *(const short8*)&Qs[(w * 2 + 1) * 512 + lane * 8];

    floatx4 acc_o[4];
    #pragma unroll
    for (int dbi = 0; dbi < 4; ++dbi) acc_o[dbi] = (floatx4){0.f, 0.f, 0.f, 0.f};
    float l_lane = 0.f;
    const int myq = w * 16 + col;

    for (int kt = 0; kt <= qt; ++kt) {
        const int cur = kt & 1;
        const ushort* Kc = Ks[cur];
        const ushort* Vc = Vs[cur];

        if (kt < qt) {
            ushort* Kn = (ushort*)Ks[cur ^ 1];
            ushort* Vn = (ushort*)Vs[cur ^ 1];
            #pragma unroll
            for (int t = 0; t < 2; ++t) {
                load_lds16(kg[t], &Kn[(w * 2 + t) * 512]);
                load_lds16(vg[t], &Vn[(w * 2 + t) * 512]);
                kg[t] += 64 * 64;
                vg[t] += 64;
            }
        }

        // ---- S^T = K Q^T ----
        floatx4 s_acc[4];
        #pragma unroll
        for (int kb = 0; kb < 4; ++kb) {
            short8 k0f = *(const short8*)&Kc[(kb * 2 + 0) * 512 + lane * 8];
            short8 k1f = *(const short8*)&Kc[(kb * 2 + 1) * 512 + lane * 8];
            floatx4 z = (floatx4){0.f, 0.f, 0.f, 0.f};
            z = __builtin_amdgcn_mfma_f32_16x16x32_bf16(k0f, a0, z, 0, 0, 0);
            z = __builtin_amdgcn_mfma_f32_16x16x32_bf16(k1f, a1, z, 0, 0, 0);
            s_acc[kb] = z;
        }

        // ---- p = exp(s/8); write P rows ----
        if (kt == qt) {
            #pragma unroll
            for (int kb = 0; kb < 4; ++kb) {
                const int kbase = kb * 16 + quad * 4;
                float p[4];
                #pragma unroll
                for (int r = 0; r < 4; ++r) {
                    float e = __expf(s_acc[kb][r] * 0.125f);
                    p[r] = (kbase + r > myq) ? 0.f : e;
                    l_lane += p[r];
                }
                uint2 u = { bfpack2(p[0], p[1]), bfpack2(p[2], p[3]) };
                *(uint2*)&Ps[myq * LP + kbase] = u;
            }
        } else {
            #pragma unroll
            for (int kb = 0; kb < 4; ++kb) {
                const int kbase = kb * 16 + quad * 4;
                float p[4];
                #pragma unroll
                for (int r = 0; r < 4; ++r) {
                    p[r] = __expf(s_acc[kb][r] * 0.125f);
                    l_lane += p[r];
                }
                uint2 u = { bfpack2(p[0], p[1]), bfpack2(p[2], p[3]) };
                *(uint2*)&Ps[myq * LP + kbase] = u;
            }
        }

        // ---- O += P V ----
        short8 pa0 = *(const short8*)&Ps[(w * 16 + col) * LP + quad * 8];
        short8 pa1 = *(const short8*)&Ps[(w * 16 + col) * LP + 32 + quad * 8];
        #pragma unroll
        for (int dbi = 0; dbi < 4; ++dbi) {
            short8 vb0 = *(const short8*)&Vc[(dbi * 2 + 0) * 512 + lane * 8];
            short8 vb1 = *(const short8*)&Vc[(dbi * 2 + 1) * 512 + lane * 8];
            acc_o[dbi] = __builtin_amdgcn_mfma_f32_16x16x32_bf16(pa0, vb0, acc_o[dbi], 0, 0, 0);
            acc_o[dbi] = __builtin_amdgcn_mfma_f32_16x16x32_bf16(pa1, vb1, acc_o[dbi], 0, 0, 0);
        }

        __syncthreads();
    }

    // ---- finalize l ----
    l_lane += __shfl_xor(l_lane, 16);
    l_lane += __shfl_xor(l_lane, 32);
    if (quad == 0) ls[w][col] = 1.f / l_lane;
    float4 invv = *(const float4*)&ls[w][quad * 4];

    #pragma unroll
    for (int dbi = 0; dbi < 4; ++dbi)
        #pragma unroll
        for (int r = 0; r < 4; ++r) {
            int q = q0 + w * 16 + quad * 4 + r;
            int d = dbi * 16 + col;
            float inv = (r == 0) ? invv.x : (r == 1) ? invv.y : (r == 2) ? invv.z : invv.w;
            out[((size_t)(b * SEQ + q)) * EMBED_DIM + h * 64 + d] = f2bf(acc_o[dbi][r] * inv);
        }
}

// ---------------------------------------------------------------------------
extern "C" void kernel_launch(void* const* d_in, const int* in_sizes, int n_in,
                              void* d_out, int out_size, void* d_ws, size_t ws_size,
                              hipStream_t stream)
{
    const float* x     = (const float*)d_in[0];
    const float* W_qkv = (const float*)d_in[1];
    const float* b_qkv = (const float*)d_in[2];
    const float* W_out = (const float*)d_in[3];
    const float* b_out = (const float*)d_in[4];
    float* out = (float*)d_out;

    const int M  = BATCH * SEQ;            // 4096
    const int D  = EMBED_DIM;              // 1024
    const int N1 = 3 * D;                  // 3072
    const size_t HE = (size_t)BATCH * NUM_HEADS * SEQ * 64;  // 4M

    ushort* xb    = (ushort*)d_ws;
    ushort* Wqb_t = xb + (size_t)M * D;
    ushort* Wob_t = Wqb_t + (size_t)D * N1;
    ushort* Qb    = Wob_t + (size_t)D * D;
    ushort* Kb    = Qb + HE;
    ushort* Vt    = Kb + HE;
    ushort* attnb = Vt + HE;

    // 0) fused prep: cast x, transpose+cast weights
    prep_all<<<5120, 256, 0, stream>>>(x, W_qkv, W_out, xb, Wqb_t, Wob_t);

    // 1) qkv projection — 256^2 8-phase v3 (asm ds_reads), 192 x 512
    gemm_qkv_8ph<<<dim3(192), 512, 0, stream>>>(xb, Wqb_t, b_qkv, Qb, Kb, Vt);

    // 2) flash attention
    attn_fused<<<dim3(32 * 32), 256, 0, stream>>>(Qb, Kb, Vt, attnb);

    // 3) output projection
    gemm_out_mfma<<<dim3(D / 128, M / 128), 256, 0, stream>>>(
        attnb, Wob_t, b_out, out);
}

// Round 4
// 191.546 us; speedup vs baseline: 1.0894x; 1.0693x over previous
//
#include <hip/hip_runtime.h>
#include <hip/hip_bf16.h>
#include <math.h>

#define EMBED_DIM 1024
#define NUM_HEADS 16
#define HEAD_DIM 64
#define BATCH 2
#define SEQ 2048

using short8  = __attribute__((ext_vector_type(8))) short;
using floatx4 = __attribute__((ext_vector_type(4))) float;

__device__ __forceinline__ ushort f2bf(float f) {
    unsigned u = __float_as_uint(f);
    u = (u + 0x7FFFu + ((u >> 16) & 1u)) >> 16;   // RNE
    return (ushort)u;
}

// pack two floats to bf16x2 (half-up rounding — P values are in [0,1], fine)
__device__ __forceinline__ unsigned bfpack2(float a, float b) {
    return ((__float_as_uint(a) + 0x8000u) >> 16) |
           (((__float_as_uint(b) + 0x8000u) >> 16) << 16);
}

// async global->LDS, 16B per lane; LDS dest = wave-uniform base + lane*16.
__device__ __forceinline__ void load_lds16(const ushort* g, ushort* l) {
    __builtin_amdgcn_global_load_lds(
        (const __attribute__((address_space(1))) void*)g,
        (__attribute__((address_space(3))) void*)l, 16, 0, 0);
}

// ---------------------------------------------------------------------------
// Fused prep: cast x -> bf16, transpose+cast W_qkv and W_out.
// ---------------------------------------------------------------------------
__device__ __forceinline__ void tc_tile(
    const float* __restrict__ W, ushort* __restrict__ Wt,
    int K, int N, int n0, int k0, float (*t)[65])
{
    const int c = threadIdx.x & 63, r0 = (threadIdx.x >> 6) * 16;
    #pragma unroll
    for (int r = 0; r < 16; ++r)
        t[r0 + r][c] = W[(size_t)(k0 + r0 + r) * N + n0 + c];
    __syncthreads();
    #pragma unroll
    for (int r = 0; r < 16; ++r)
        Wt[(size_t)(n0 + r0 + r) * K + k0 + c] = f2bf(t[c][r0 + r]);
}

__global__ __launch_bounds__(256) void prep_all(
    const float* __restrict__ x, const float* __restrict__ W_qkv,
    const float* __restrict__ W_out,
    ushort* __restrict__ xb, ushort* __restrict__ Wqb_t, ushort* __restrict__ Wob_t)
{
    __shared__ float t[64][65];
    const int bx = blockIdx.x;
    if (bx < 4096) {
        int i = (bx * 256 + threadIdx.x) * 4;
        float4 v = *(const float4*)&x[i];
        ushort4 o = { f2bf(v.x), f2bf(v.y), f2bf(v.z), f2bf(v.w) };
        *(ushort4*)&xb[i] = o;
    } else if (bx < 4096 + 768) {
        int b = bx - 4096;
        tc_tile(W_qkv, Wqb_t, 1024, 3072, (b % 48) * 64, (b / 48) * 64, t);
    } else {
        int b = bx - 4864;
        tc_tile(W_out, Wob_t, 1024, 1024, (b % 16) * 64, (b / 16) * 64, t);
    }
}

// ---------------------------------------------------------------------------
// bf16 MFMA GEMM core, double-buffered: C[128x128] = A[m0:,K] @ Bt[n0:,K]^T.
// Issue-early prefetch, one barrier per K-step (proven 46.5us structure).
//
// NEW (round 3): both-sides LDS chunk swizzle to kill the 3.1M bank
// conflicts. The LDS tile is [128 rows][4 chunks of 16B]. Linear chunk c of
// row r holds LOGICAL chunk c ^ s(r), s(r) = (r>>1)&3:
//   - staging source: lane (4 lanes/row) reads global chunk
//     (lane&3) ^ ((lane>>3)&3)  [= c ^ s(row0), row0 = w*32 + (lane>>2)];
//     same 64B lines as before, permuted per 4-lane group -> coalescing kept;
//     LDS dest stays linear (global_load_lds requirement).
//   - fragment read: logical chunk `quad` of row r -> linear chunk
//     quad ^ ((col>>1)&3)   [row ≡ col (mod 16), higher row bits ≡ 0 mod 4].
// Per 16-lane phase group this gives 8 distinct 4-bank groups x 2 lanes
// (2-way = free, m136) instead of 2 groups x 8 lanes (4-way conflict).
// ---------------------------------------------------------------------------
#define GK 1024

__device__ __forceinline__ void gemm_core(
    const ushort* __restrict__ A, const ushort* __restrict__ Bt,
    int m0, int n0, ushort* As0, ushort* As1, ushort* Bs0, ushort* Bs1,
    floatx4 acc[4][4])
{
    const int tid  = threadIdx.x;
    const int w    = tid >> 6;
    const int lane = tid & 63;
    const int col  = lane & 15;
    const int quad = lane >> 4;
    const int wm   = w >> 1, wn = w & 1;

    #pragma unroll
    for (int i = 0; i < 4; ++i)
        #pragma unroll
        for (int j = 0; j < 4; ++j)
            acc[i][j] = (floatx4){0.f, 0.f, 0.f, 0.f};

    const int o0   = w * 2048 + lane * 16;   // byte offset in 8KB tile
    const int row0 = o0 >> 6;
    // swizzled source chunk: (c ^ s(row0)) * 8 ushorts
    const int ke0  = ((lane & 3) ^ ((lane >> 3) & 3)) * 8;
    const int loff = (w * 2048) >> 1;        // LDS element offset for this wave

    const ushort* ga = A  + (size_t)(m0 + row0) * GK + ke0;
    const ushort* gb = Bt + (size_t)(n0 + row0) * GK + ke0;

    // prologue: stage k=0 into buffer 0
    #pragma unroll
    for (int t = 0; t < 2; ++t) {
        load_lds16(ga + (size_t)t * 16 * GK, As0 + loff + t * 512);
        load_lds16(gb + (size_t)t * 16 * GK, Bs0 + loff + t * 512);
    }
    __syncthreads();

    // swizzled read chunk for this lane (same for A and B: row ≡ col mod 16)
    const int sq = (quad ^ ((col >> 1) & 3)) * 8;

    for (int k0 = 0; k0 < GK; k0 += 32) {
        const int cur = (k0 >> 5) & 1;
        ushort* Ac = cur ? As1 : As0;
        ushort* Bc = cur ? Bs1 : Bs0;
        ushort* An = cur ? As0 : As1;
        ushort* Bn = cur ? Bs0 : Bs1;

        if (k0 + 32 < GK) {   // issue prefetch BEFORE compute
            #pragma unroll
            for (int t = 0; t < 2; ++t) {
                load_lds16(ga + (k0 + 32) + (size_t)t * 16 * GK, An + loff + t * 512);
                load_lds16(gb + (k0 + 32) + (size_t)t * 16 * GK, Bn + loff + t * 512);
            }
        }

        short8 af[4], bf[4];
        #pragma unroll
        for (int i = 0; i < 4; ++i)
            af[i] = *(const short8*)&Ac[(wm * 64 + i * 16 + col) * 32 + sq];
        #pragma unroll
        for (int j = 0; j < 4; ++j)
            bf[j] = *(const short8*)&Bc[(wn * 64 + j * 16 + col) * 32 + sq];
        #pragma unroll
        for (int i = 0; i < 4; ++i)
            #pragma unroll
            for (int j = 0; j < 4; ++j)
                acc[i][j] = __builtin_amdgcn_mfma_f32_16x16x32_bf16(af[i], bf[j], acc[i][j], 0, 0, 0);

        __syncthreads();   // prefetch landed (covered by the MFMAs above);
                           // also fences cur-buffer reuse two iters later
    }
}

// GEMM1: qkv projection; fused split/cast; V emitted transposed.
__global__ __launch_bounds__(256) void gemm_qkv_mfma(
    const ushort* __restrict__ A, const ushort* __restrict__ Bt,
    const float* __restrict__ bias,
    ushort* __restrict__ Qb, ushort* __restrict__ Kb, ushort* __restrict__ Vt)
{
    __shared__ __align__(16) ushort As[2][128 * 32];
    __shared__ __align__(16) ushort Bs[2][128 * 32];
    const int n0 = blockIdx.x * 128;
    const int m0 = blockIdx.y * 128;

    floatx4 acc[4][4];
    gemm_core(A, Bt, m0, n0, As[0], As[1], Bs[0], Bs[1], acc);

    const int lane = threadIdx.x & 63;
    const int w    = threadIdx.x >> 6;
    const int col  = lane & 15, quad = lane >> 4;
    const int wm   = w >> 1, wn = w & 1;

    #pragma unroll
    for (int j = 0; j < 4; ++j) {
        const int n = n0 + wn * 64 + j * 16 + col;
        const float bj = bias[n];
        const int part = n >> 10;
        const int h = (n >> 6) & 15;
        const int d = n & 63;
        #pragma unroll
        for (int i = 0; i < 4; ++i)
            #pragma unroll
            for (int r = 0; r < 4; ++r) {
                const int m = m0 + wm * 64 + i * 16 + quad * 4 + r;
                const int b = m >> 11, s = m & 2047;
                const int bh = b * 16 + h;
                const ushort bv = f2bf(acc[i][j][r] + bj);
                if (part == 0)      Qb[((size_t)bh * SEQ + s) * 64 + d] = bv;
                else if (part == 1) Kb[((size_t)bh * SEQ + s) * 64 + d] = bv;
                else                Vt[((size_t)bh * 64 + d) * SEQ + s] = bv;
            }
    }
}

// GEMM2: out = attn_b @ W_out + b_out -> fp32
__global__ __launch_bounds__(256) void gemm_out_mfma(
    const ushort* __restrict__ A, const ushort* __restrict__ Bt,
    const float* __restrict__ bias, float* __restrict__ out)
{
    __shared__ __align__(16) ushort As[2][128 * 32];
    __shared__ __align__(16) ushort Bs[2][128 * 32];
    const int n0 = blockIdx.x * 128;
    const int m0 = blockIdx.y * 128;

    floatx4 acc[4][4];
    gemm_core(A, Bt, m0, n0, As[0], As[1], Bs[0], Bs[1], acc);

    const int lane = threadIdx.x & 63;
    const int w    = threadIdx.x >> 6;
    const int col  = lane & 15, quad = lane >> 4;
    const int wm   = w >> 1, wn = w & 1;

    #pragma unroll
    for (int j = 0; j < 4; ++j) {
        const int n = n0 + wn * 64 + j * 16 + col;
        const float bj = bias[n];
        #pragma unroll
        for (int i = 0; i < 4; ++i)
            #pragma unroll
            for (int r = 0; r < 4; ++r) {
                const int m = m0 + wm * 64 + i * 16 + quad * 4 + r;
                out[(size_t)m * EMBED_DIM + n] = acc[i][j][r] + bj;
            }
    }
}

// ---------------------------------------------------------------------------
// Flash attention, bf16 MFMA, fragment-ordered async staging, S^T softmax,
// double-buffered K/V with issue-early prefetch (1 barrier per key-tile).
// ---------------------------------------------------------------------------
#define LP 72

__global__ __launch_bounds__(256) void attn_fused(
    const ushort* __restrict__ Qb, const ushort* __restrict__ Kb,
    const ushort* __restrict__ Vt, ushort* __restrict__ out)
{
    const int id = blockIdx.x;
    const int qt = 31 - (id >> 5);          // reversed: long blocks first (LPT)
    const int bh = id & 31;
    const int b  = bh >> 4, h = bh & 15;
    const int q0 = qt * 64;

    __shared__ __align__(16) ushort Qs[8 * 512];        // 8 KB fragment order
    __shared__ __align__(16) ushort Ks[2][8 * 512];     // 16 KB dbuf
    __shared__ __align__(16) ushort Vs[2][8 * 512];     // 16 KB dbuf
    __shared__ __align__(16) ushort Ps[64 * LP];        // 9 KB
    __shared__ __align__(16) float  ls[4][16];

    const int tid  = threadIdx.x;
    const int w    = tid >> 6;
    const int lane = tid & 63;
    const int col  = lane & 15;
    const int quad = lane >> 4;

    // per-lane global staging pointers (fragment-order gather)
    const ushort* kg[2];
    const ushort* vg[2];
    #pragma unroll
    for (int t = 0; t < 2; ++t) {
        kg[t] = Kb + (size_t)bh * SEQ * 64 + (size_t)(w * 16 + col) * 64 + t * 32 + quad * 8;
        vg[t] = Vt + (size_t)bh * 64 * SEQ + (size_t)(w * 16 + col) * SEQ + t * 32 + quad * 8;
    }

    // prologue: stage Q + K/V tile 0 into buffer 0
    {
        const ushort* Qg = Qb + ((size_t)bh * SEQ + q0) * 64;
        #pragma unroll
        for (int t = 0; t < 2; ++t) {
            load_lds16(Qg + (size_t)(w * 16 + col) * 64 + t * 32 + quad * 8,
                       &Qs[(w * 2 + t) * 512]);
            load_lds16(kg[t], &Ks[0][(w * 2 + t) * 512]);
            load_lds16(vg[t], &Vs[0][(w * 2 + t) * 512]);
            kg[t] += 64 * 64;   // -> tile 1
            vg[t] += 64;
        }
    }
    __syncthreads();

    const short8 a0 = *(const short8*)&Qs[(w * 2 + 0) * 512 + lane * 8];
    const short8 a1 = *(const short8*)&Qs[(w * 2 + 1) * 512 + lane * 8];

    floatx4 acc_o[4];
    #pragma unroll
    for (int dbi = 0; dbi < 4; ++dbi) acc_o[dbi] = (floatx4){0.f, 0.f, 0.f, 0.f};
    float l_lane = 0.f;
    const int myq = w * 16 + col;           // tile-local query owned in S^T

    for (int kt = 0; kt <= qt; ++kt) {
        const int cur = kt & 1;
        const ushort* Kc = Ks[cur];
        const ushort* Vc = Vs[cur];

        if (kt < qt) {   // issue-early prefetch of next tile into other buffer
            ushort* Kn = (ushort*)Ks[cur ^ 1];
            ushort* Vn = (ushort*)Vs[cur ^ 1];
            #pragma unroll
            for (int t = 0; t < 2; ++t) {
                load_lds16(kg[t], &Kn[(w * 2 + t) * 512]);
                load_lds16(vg[t], &Vn[(w * 2 + t) * 512]);
                kg[t] += 64 * 64;
                vg[t] += 64;
            }
        }

        // ---- S^T = K Q^T ----
        floatx4 s_acc[4];
        #pragma unroll
        for (int kb = 0; kb < 4; ++kb) {
            short8 k0f = *(const short8*)&Kc[(kb * 2 + 0) * 512 + lane * 8];
            short8 k1f = *(const short8*)&Kc[(kb * 2 + 1) * 512 + lane * 8];
            floatx4 z = (floatx4){0.f, 0.f, 0.f, 0.f};
            z = __builtin_amdgcn_mfma_f32_16x16x32_bf16(k0f, a0, z, 0, 0, 0);
            z = __builtin_amdgcn_mfma_f32_16x16x32_bf16(k1f, a1, z, 0, 0, 0);
            s_acc[kb] = z;   // lane: query col; regs: keys kb*16+quad*4+r
        }

        // ---- p = exp(s/8); write P rows (ds_write_b64 each) ----
        if (kt == qt) {
            #pragma unroll
            for (int kb = 0; kb < 4; ++kb) {
                const int kbase = kb * 16 + quad * 4;
                float p[4];
                #pragma unroll
                for (int r = 0; r < 4; ++r) {
                    float e = __expf(s_acc[kb][r] * 0.125f);
                    p[r] = (kbase + r > myq) ? 0.f : e;
                    l_lane += p[r];
                }
                uint2 u = { bfpack2(p[0], p[1]), bfpack2(p[2], p[3]) };
                *(uint2*)&Ps[myq * LP + kbase] = u;
            }
        } else {
            #pragma unroll
            for (int kb = 0; kb < 4; ++kb) {
                const int kbase = kb * 16 + quad * 4;
                float p[4];
                #pragma unroll
                for (int r = 0; r < 4; ++r) {
                    p[r] = __expf(s_acc[kb][r] * 0.125f);
                    l_lane += p[r];
                }
                uint2 u = { bfpack2(p[0], p[1]), bfpack2(p[2], p[3]) };
                *(uint2*)&Ps[myq * LP + kbase] = u;
            }
        }

        // ---- O += P V  (Ps rows wave-private) ----
        short8 pa0 = *(const short8*)&Ps[(w * 16 + col) * LP + quad * 8];
        short8 pa1 = *(const short8*)&Ps[(w * 16 + col) * LP + 32 + quad * 8];
        #pragma unroll
        for (int dbi = 0; dbi < 4; ++dbi) {
            short8 vb0 = *(const short8*)&Vc[(dbi * 2 + 0) * 512 + lane * 8];
            short8 vb1 = *(const short8*)&Vc[(dbi * 2 + 1) * 512 + lane * 8];
            acc_o[dbi] = __builtin_amdgcn_mfma_f32_16x16x32_bf16(pa0, vb0, acc_o[dbi], 0, 0, 0);
            acc_o[dbi] = __builtin_amdgcn_mfma_f32_16x16x32_bf16(pa1, vb1, acc_o[dbi], 0, 0, 0);
        }

        __syncthreads();   // prefetch landed (covered by compute above);
                           // fences cur-buffer overwrite two iters later
    }

    // ---- finalize l ----
    l_lane += __shfl_xor(l_lane, 16);
    l_lane += __shfl_xor(l_lane, 32);
    if (quad == 0) ls[w][col] = 1.f / l_lane;   // wave-private
    float4 invv = *(const float4*)&ls[w][quad * 4];

    #pragma unroll
    for (int dbi = 0; dbi < 4; ++dbi)
        #pragma unroll
        for (int r = 0; r < 4; ++r) {
            int q = q0 + w * 16 + quad * 4 + r;
            int d = dbi * 16 + col;
            float inv = (r == 0) ? invv.x : (r == 1) ? invv.y : (r == 2) ? invv.z : invv.w;
            out[((size_t)(b * SEQ + q)) * EMBED_DIM + h * 64 + d] = f2bf(acc_o[dbi][r] * inv);
        }
}

// ---------------------------------------------------------------------------
extern "C" void kernel_launch(void* const* d_in, const int* in_sizes, int n_in,
                              void* d_out, int out_size, void* d_ws, size_t ws_size,
                              hipStream_t stream)
{
    const float* x     = (const float*)d_in[0];
    const float* W_qkv = (const float*)d_in[1];
    const float* b_qkv = (const float*)d_in[2];
    const float* W_out = (const float*)d_in[3];
    const float* b_out = (const float*)d_in[4];
    float* out = (float*)d_out;

    const int M  = BATCH * SEQ;            // 4096
    const int D  = EMBED_DIM;              // 1024
    const int N1 = 3 * D;                  // 3072
    const size_t HE = (size_t)BATCH * NUM_HEADS * SEQ * 64;  // 4M

    ushort* xb    = (ushort*)d_ws;
    ushort* Wqb_t = xb + (size_t)M * D;
    ushort* Wob_t = Wqb_t + (size_t)D * N1;
    ushort* Qb    = Wob_t + (size_t)D * D;
    ushort* Kb    = Qb + HE;
    ushort* Vt    = Kb + HE;
    ushort* attnb = Vt + HE;

    // 0) fused prep: cast x, transpose+cast weights
    prep_all<<<5120, 256, 0, stream>>>(x, W_qkv, W_out, xb, Wqb_t, Wob_t);

    // 1) qkv projection
    gemm_qkv_mfma<<<dim3(N1 / 128, M / 128), 256, 0, stream>>>(
        xb, Wqb_t, b_qkv, Qb, Kb, Vt);

    // 2) flash attention
    attn_fused<<<dim3(32 * 32), 256, 0, stream>>>(Qb, Kb, Vt, attnb);

    // 3) output projection
    gemm_out_mfma<<<dim3(D / 128, M / 128), 256, 0, stream>>>(
        attnb, Wob_t, b_out, out);
}